// Round 2
// baseline (604.319 us; speedup 1.0000x reference)
//
#include <hip/hip_runtime.h>

// LSS-FPN round 12: conv rebuilt as in-block K-split, barrier-free loop.
// Block = 128 thr = 2 waves; tile 64sp x 32co; wave h computes ci half h
// (M2N1 fragments, 3 ds_read_b128 per 2 MFMAs). Waves touch byte-disjoint
// LDS -> NO barriers in kc loop; one syncthreads at end for the fp32
// cross-half reduction (wave1 dumps acc into its own dead X region).
// Grid 1056 blocks/layer (11sp x 16co x 6img), dual 2112; 39.5 KB LDS ->
// 4 blocks/CU = 8 waves/CU. gemm1x1 d2+c2 merged into one 72-block dispatch.

#define FH_ 16
#define FW_ 44
#define SP_ 704
#define XSTR 960         // xt rows per image (incl. halo slack)
#define NIMG 6
#define CIN 512
#define DCH 112
#define CCTX 80
#define NXY 128
#define NVOX (NXY * NXY)
#define NPTS (NIMG * DCH * SP_)
#define CHUNK 64

#define XW 24            // X LDS row stride (shorts) = 48 B
#define WW 40            // W LDS row stride (shorts) = 80 B (both ci halves)
#define XHROWS 171       // X region rows per half (8208 B >= 8 KB acc dump)
#define XSROWS 162       // staged X rows (64px window + 3x3 halo)
#define XHALF (XHROWS * XW)          // 4104 shorts per X half region
#define WBASE (2 * XHALF)            // 8208
#define LDS_SHORTS (WBASE + 9 * 32 * WW)   // 19728 shorts = 39,456 B
#define TPL2 1056        // conv tiles per layer: 11sp * 16co * 6img
#define CIP 40           // padded LDS k-stride for gemm1x1 (shorts)

typedef unsigned short u16;
typedef __attribute__((ext_vector_type(8))) short bf16x8;
typedef __attribute__((ext_vector_type(4))) float f32x4;
typedef __attribute__((ext_vector_type(16))) float f32x16;

__device__ __forceinline__ float bf2f(u16 b) {
    union { unsigned u; float f; } v; v.u = ((unsigned)b) << 16; return v.f;
}
__device__ __forceinline__ u16 f2bf(float f) {
    union { float f; unsigned u; } v; v.f = f;
    unsigned r = v.u + 0x7fffu + ((v.u >> 16) & 1u);   // RTNE
    return (u16)(r >> 16);
}
__device__ __forceinline__ int spad_of(int s) {
    return (s / 44) * 46 + (s % 44) + 47;
}

// ---------------- zero fill ---------------------------------------------------
__global__ void zero_k(float4* __restrict__ p, long n4) {
    long i = (long)blockIdx.x * blockDim.x + threadIdx.x;
    if (i < n4) p[i] = make_float4(0.f, 0.f, 0.f, 0.f);
}

// ---------------- src fp32 [n][ci][704] -> xt bf16 [n][XSTR][512] -------------
__global__ void src_to_xt_k(const float* __restrict__ src, short* __restrict__ xt) {
    int e = blockIdx.x * 256 + threadIdx.x;
    if (e >= NIMG * SP_ * CIN) return;
    int ci = e & 511;
    int r = e >> 9;
    int s = r % SP_, n = r / SP_;
    float v = src[((size_t)n * CIN + ci) * SP_ + s];
    xt[((size_t)n * XSTR + spad_of(s)) * 512 + ci] = (short)f2bf(v);
}

// ---------------- weight convert: fp32 [co][ci][9] -> bf16 [t][co][ci] --------
__global__ void wsplit_k(const float* __restrict__ w, short* __restrict__ hi) {
    int e = blockIdx.x * 256 + threadIdx.x;
    if (e >= CIN * CIN) return;
    const float* wp = w + (size_t)e * 9;
#pragma unroll
    for (int t = 0; t < 9; ++t)
        hi[(size_t)t * (CIN * CIN) + e] = (short)f2bf(wp[t]);
}

// dual: converts two 3x3 weight tensors in one dispatch
__global__ void wsplit_dual_k(const float* __restrict__ w1, short* __restrict__ o1,
                              const float* __restrict__ w2, short* __restrict__ o2) {
    int i = blockIdx.x * 256 + threadIdx.x;
    if (i >= 2 * CIN * CIN) return;
    int e = i & (CIN * CIN - 1);
    const float* w = (i < CIN * CIN) ? w1 : w2;
    short* o = (i < CIN * CIN) ? o1 : o2;
    const float* wp = w + (size_t)e * 9;
#pragma unroll
    for (int t = 0; t < 9; ++t)
        o[(size_t)t * (CIN * CIN) + e] = (short)f2bf(wp[t]);
}

// dual 1x1 weights fp32 [co][ci] -> bf16
__global__ void wsplit1_dual_k(const float* __restrict__ wd, short* __restrict__ od,
                               const float* __restrict__ wc, short* __restrict__ oc) {
    int i = blockIdx.x * 256 + threadIdx.x;
    if (i < DCH * CIN) od[i] = (short)f2bf(wd[i]);
    else if (i < DCH * CIN + CCTX * CIN) {
        int j = i - DCH * CIN;
        oc[j] = (short)f2bf(wc[j]);
    }
}

// ---------------- conv3x3+relu, in-block K-split, barrier-free ---------------
// tile id: [layer][img][co_blk (16)][sp_blk (11)]; layer B iff tile >= TPL2.
__global__ __launch_bounds__(128, 2) void conv3s_k(
    const short* __restrict__ xt,
    const short* __restrict__ wA, short* __restrict__ outA,
    const short* __restrict__ wB, short* __restrict__ outB,
    int ntiles)
{
    __shared__ short L[LDS_SHORTS];
    int t = blockIdx.x;
    if (t >= ntiles) return;

    const int tid = threadIdx.x;
    const int lane = tid & 63;
    const int h = tid >> 6;             // wave index = ci half
    const int l31 = lane & 31, lh = lane >> 5;

    int layer = 0;
    if (t >= TPL2) { layer = 1; t -= TPL2; }
    const int n = t / 176;
    const int rem = t - n * 176;
    const int cb = rem / 11;
    const int sb = rem - cb * 11;
    const short* __restrict__ wth = layer ? wB : wA;
    short* __restrict__ xout = layer ? outB : outA;

    const int s0 = sb * 64;
    const int co0 = cb * 32;
    const int base = spad_of(s0) - 47;
    const short* xbh = xt + ((size_t)n * XSTR + base) * 512 + h * 256;

    short* Xb = &L[h * XHALF];
    short* Wb = &L[WBASE];

    int sloc[2];
#pragma unroll
    for (int mf = 0; mf < 2; ++mf)
        sloc[mf] = spad_of(s0 + mf * 32 + l31) - base;

    const f32x16 z16 = {0.f,0.f,0.f,0.f,0.f,0.f,0.f,0.f,
                        0.f,0.f,0.f,0.f,0.f,0.f,0.f,0.f};
    f32x16 acc[2];
    acc[0] = z16; acc[1] = z16;

    for (int kc = 0; kc < 16; ++kc) {
        const int kof = kc * 16;
        // stage own X half: 162 rows x 2 chunks = 324 tasks over 64 lanes
#pragma unroll
        for (int it = 0; it < 6; ++it) {
            int q = it * 64 + lane;
            if (q < XSROWS * 2) {
                int row = q >> 1, hh = q & 1;
                *(bf16x8*)&Xb[row * XW + hh * 8] =
                    *(const bf16x8*)(xbh + (size_t)row * 512 + kof + hh * 8);
            }
        }
        // stage own W half into its 16-short sub-slot: 288 rows x 2 = 576 tasks
#pragma unroll
        for (int it = 0; it < 9; ++it) {
            int q = it * 64 + lane;
            int wr = q >> 1, c = q & 1;
            *(bf16x8*)&Wb[wr * WW + h * 16 + c * 8] =
                *(const bf16x8*)(wth + ((size_t)(wr >> 5) * CIN + co0 + (wr & 31)) * CIN
                                 + h * 256 + kof + c * 8);
        }
        constexpr int OFF[9] = {-47, -46, -45, -1, 0, 1, 45, 46, 47};
#pragma unroll
        for (int t9 = 0; t9 < 9; ++t9) {
            const int off = OFF[t9];
            bf16x8 a0 = *(const bf16x8*)&Xb[(sloc[0] + off) * XW + lh * 8];
            bf16x8 a1 = *(const bf16x8*)&Xb[(sloc[1] + off) * XW + lh * 8];
            bf16x8 b0 = *(const bf16x8*)&Wb[(t9 * 32 + l31) * WW + h * 16 + lh * 8];
            acc[0] = __builtin_amdgcn_mfma_f32_32x32x16_bf16(a0, b0, acc[0], 0, 0, 0);
            acc[1] = __builtin_amdgcn_mfma_f32_32x32x16_bf16(a1, b0, acc[1], 0, 0, 0);
        }
    }

    // cross-half reduction: wave1 dumps acc into its own (dead) X region.
    float* D = (float*)&L[XHALF];       // 8192 B needed, 8208 B available
    if (h == 1) {
#pragma unroll
        for (int mf = 0; mf < 2; ++mf)
#pragma unroll
            for (int r = 0; r < 16; ++r) {
                int sp = mf * 32 + 4 * lh + (r & 3) + 8 * (r >> 2);
                D[sp * 32 + l31] = acc[mf][r];
            }
    }
    __syncthreads();
    if (h == 0) {
#pragma unroll
        for (int mf = 0; mf < 2; ++mf)
#pragma unroll
            for (int r = 0; r < 16; ++r) {
                int sp = mf * 32 + 4 * lh + (r & 3) + 8 * (r >> 2);
                float v = fmaxf(acc[mf][r] + D[sp * 32 + l31], 0.f);
                xout[((size_t)n * XSTR + spad_of(s0 + sp)) * 512 + co0 + l31] =
                    (short)f2bf(v);
            }
    }
}

// ---------------- merged 1x1 convs (d2 + c2) as GEMM -------------------------
// grid (6, 2, 6): y=0 -> depth head (NCO=112), y=1 -> context head (NCO=80).
__global__ __launch_bounds__(256, 2) void gemm1x1d_k(
    const short* __restrict__ xA, const short* __restrict__ wA,
    const float* __restrict__ bA, float* __restrict__ oA,
    const short* __restrict__ xB, const short* __restrict__ wB,
    const float* __restrict__ bB, float* __restrict__ oB)
{
    const int sel = blockIdx.y;
    const short* __restrict__ xtin = sel ? xB : xA;
    const short* __restrict__ wb   = sel ? wB : wA;
    const float* __restrict__ bias = sel ? bB : bA;
    float* __restrict__ outT       = sel ? oB : oA;
    const int nst = sel ? (CCTX / 16) : (DCH / 16);   // 5 or 7
    const int nco = nst * 16;

    __shared__ short Wb[DCH * CIP];
    const int tid = threadIdx.x;
    const int s0 = blockIdx.x * 128, n = blockIdx.z;
    const int lane = tid & 63, wave = tid >> 6;
    const int kg = lane >> 4, lrow = lane & 15;
    const int swave = s0 + wave * 32;

    int arow[2];
#pragma unroll
    for (int ms = 0; ms < 2; ++ms)
        arow[ms] = spad_of(swave + ms * 16 + lrow);

    const f32x4 zero4 = {0.f, 0.f, 0.f, 0.f};
    f32x4 acc[2][7];
#pragma unroll
    for (int ms = 0; ms < 2; ++ms)
#pragma unroll
        for (int ns = 0; ns < 7; ++ns) acc[ms][ns] = zero4;

    const short* xb = xtin + (size_t)n * XSTR * 512;

    for (int kc = 0; kc < 16; ++kc) {
        __syncthreads();
#pragma unroll
        for (int it = 0; it < 2; ++it) {
            int q = it * 256 + tid;
            if (q < nco * 4) {
                int co = q >> 2, p = q & 3;
                *(bf16x8*)&Wb[co * CIP + p * 8] =
                    *(const bf16x8*)(wb + (size_t)co * CIN + kc * 32 + p * 8);
            }
        }
        __syncthreads();
        bf16x8 a[2];
#pragma unroll
        for (int ms = 0; ms < 2; ++ms)
            a[ms] = *(const bf16x8*)(xb + (size_t)arow[ms] * 512 + kc * 32 + kg * 8);
#pragma unroll
        for (int ns = 0; ns < 7; ++ns) {
            if (ns < nst) {
                int co = ns * 16 + lrow;
                bf16x8 b = *(const bf16x8*)&Wb[co * CIP + kg * 8];
#pragma unroll
                for (int ms = 0; ms < 2; ++ms)
                    acc[ms][ns] = __builtin_amdgcn_mfma_f32_16x16x32_bf16(
                        a[ms], b, acc[ms][ns], 0, 0, 0);
            }
        }
    }
#pragma unroll
    for (int ms = 0; ms < 2; ++ms)
#pragma unroll
        for (int ns = 0; ns < 7; ++ns) {
            if (ns < nst) {
#pragma unroll
                for (int r = 0; r < 4; ++r) {
                    int sg = swave + ms * 16 + kg * 4 + r;
                    if (sg < SP_) {
                        int co = ns * 16 + lrow;
                        outT[((size_t)n * SP_ + sg) * nco + co] = acc[ms][ns][r] + bias[co];
                    }
                }
            }
        }
}

// ---------------- softmax over d, layout [n][s][112] (d contiguous) ----------
__global__ __launch_bounds__(256) void softmax2_k(
    const float* __restrict__ lg, float* __restrict__ pr)
{
    const int p = blockIdx.x * 4 + (threadIdx.x >> 6);
    if (p >= NIMG * SP_) return;
    const int lane = threadIdx.x & 63;
    const float* lp = lg + (size_t)p * DCH;
    float v0 = lp[lane];
    float v1 = (lane < DCH - 64) ? lp[64 + lane] : -1e30f;
    float m = fmaxf(v0, v1);
#pragma unroll
    for (int o = 32; o; o >>= 1) m = fmaxf(m, __shfl_xor(m, o));
    float e0 = __expf(v0 - m);
    float e1 = (lane < DCH - 64) ? __expf(v1 - m) : 0.f;
    float s = e0 + e1;
#pragma unroll
    for (int o = 32; o; o >>= 1) s += __shfl_xor(s, o);
    const float inv = 1.f / s;
    float* pp = pr + (size_t)p * DCH;
    pp[lane] = e0 * inv;
    if (lane < DCH - 64) pp[64 + lane] = e1 * inv;
}

// ---------------- per-camera geometry constants (fp64, closed-form) ----------
__device__ __forceinline__ void inv4(const double* M, double* inv) {
    inv[0]  =  M[5]*M[10]*M[15] - M[5]*M[11]*M[14] - M[9]*M[6]*M[15] + M[9]*M[7]*M[14] + M[13]*M[6]*M[11] - M[13]*M[7]*M[10];
    inv[4]  = -M[4]*M[10]*M[15] + M[4]*M[11]*M[14] + M[8]*M[6]*M[15] - M[8]*M[7]*M[14] - M[12]*M[6]*M[11] + M[12]*M[7]*M[10];
    inv[8]  =  M[4]*M[9]*M[15]  - M[4]*M[11]*M[13] - M[8]*M[5]*M[15] + M[8]*M[7]*M[13] + M[12]*M[5]*M[11] - M[12]*M[7]*M[9];
    inv[12] = -M[4]*M[9]*M[14]  + M[4]*M[10]*M[13] + M[8]*M[5]*M[14] - M[8]*M[6]*M[13] - M[12]*M[5]*M[10] + M[12]*M[6]*M[9];
    inv[1]  = -M[1]*M[10]*M[15] + M[1]*M[11]*M[14] + M[9]*M[2]*M[15] - M[9]*M[3]*M[14] - M[13]*M[2]*M[11] + M[13]*M[3]*M[10];
    inv[5]  =  M[0]*M[10]*M[15] - M[0]*M[11]*M[14] - M[8]*M[2]*M[15] + M[8]*M[3]*M[14] + M[12]*M[2]*M[11] - M[12]*M[3]*M[10];
    inv[9]  = -M[0]*M[9]*M[15]  + M[0]*M[11]*M[13] + M[8]*M[1]*M[15] - M[8]*M[3]*M[13] - M[12]*M[1]*M[11] + M[12]*M[3]*M[9];
    inv[13] =  M[0]*M[9]*M[14]  - M[0]*M[10]*M[13] - M[8]*M[1]*M[14] + M[8]*M[2]*M[13] + M[12]*M[1]*M[10] - M[12]*M[2]*M[9];
    inv[2]  =  M[1]*M[6]*M[15]  - M[1]*M[7]*M[14]  - M[5]*M[2]*M[15] + M[5]*M[3]*M[14] + M[13]*M[2]*M[7]  - M[13]*M[3]*M[6];
    inv[6]  = -M[0]*M[6]*M[15]  + M[0]*M[7]*M[14]  + M[4]*M[2]*M[15] - M[4]*M[3]*M[14] - M[12]*M[2]*M[7]  + M[12]*M[3]*M[6];
    inv[10] =  M[0]*M[5]*M[15]  - M[0]*M[7]*M[13]  - M[4]*M[1]*M[15] + M[4]*M[3]*M[13] + M[12]*M[1]*M[7]  - M[12]*M[3]*M[5];
    inv[14] = -M[0]*M[5]*M[14]  + M[0]*M[6]*M[13]  + M[4]*M[1]*M[14] - M[4]*M[2]*M[13] - M[12]*M[1]*M[6]  + M[12]*M[2]*M[5];
    inv[3]  = -M[1]*M[6]*M[11]  + M[1]*M[7]*M[10]  + M[5]*M[2]*M[11] - M[5]*M[3]*M[10] - M[9]*M[2]*M[7]   + M[9]*M[3]*M[6];
    inv[7]  =  M[0]*M[6]*M[11]  - M[0]*M[7]*M[10]  - M[4]*M[2]*M[11] + M[4]*M[3]*M[10] + M[8]*M[2]*M[7]   - M[8]*M[3]*M[6];
    inv[11] = -M[0]*M[5]*M[11]  + M[0]*M[7]*M[9]   + M[4]*M[1]*M[11] - M[4]*M[3]*M[9]  - M[8]*M[1]*M[7]   + M[8]*M[3]*M[5];
    inv[15] =  M[0]*M[5]*M[10]  - M[0]*M[6]*M[9]   - M[4]*M[1]*M[10] + M[4]*M[2]*M[9]  + M[8]*M[1]*M[6]   - M[8]*M[2]*M[5];
    double det = M[0]*inv[0] + M[1]*inv[4] + M[2]*inv[8] + M[3]*inv[12];
    double id = 1.0 / det;
#pragma unroll
    for (int i = 0; i < 16; ++i) inv[i] *= id;
}

__global__ void geom_setup_k(const float* __restrict__ s2e, const float* __restrict__ intrin,
                             const float* __restrict__ ida, const float* __restrict__ bda,
                             double* __restrict__ gc)
{
    const int n = threadIdx.x;
    if (n >= NIMG) return;
    double M[16], Iv[16];
#pragma unroll
    for (int i = 0; i < 16; ++i) M[i] = (double)ida[n * 16 + i];
    inv4(M, Iv);
    double R[3][3], tv[3];
#pragma unroll
    for (int r = 0; r < 3; ++r) {
#pragma unroll
        for (int c = 0; c < 3; ++c) R[r][c] = Iv[r * 4 + c];
        tv[r] = Iv[r * 4 + 3];
    }
    double K[3][3];
#pragma unroll
    for (int r = 0; r < 3; ++r)
#pragma unroll
        for (int c = 0; c < 3; ++c) K[r][c] = (double)intrin[n * 16 + r * 4 + c];
    double det = K[0][0] * (K[1][1] * K[2][2] - K[1][2] * K[2][1])
               - K[0][1] * (K[1][0] * K[2][2] - K[1][2] * K[2][0])
               + K[0][2] * (K[1][0] * K[2][1] - K[1][1] * K[2][0]);
    double id = 1.0 / det;
    double Ki[3][3];
    Ki[0][0] = (K[1][1] * K[2][2] - K[1][2] * K[2][1]) * id;
    Ki[0][1] = (K[0][2] * K[2][1] - K[0][1] * K[2][2]) * id;
    Ki[0][2] = (K[0][1] * K[1][2] - K[0][2] * K[1][1]) * id;
    Ki[1][0] = (K[1][2] * K[2][0] - K[1][0] * K[2][2]) * id;
    Ki[1][1] = (K[0][0] * K[2][2] - K[0][2] * K[2][0]) * id;
    Ki[1][2] = (K[0][2] * K[1][0] - K[0][0] * K[1][2]) * id;
    Ki[2][0] = (K[1][0] * K[2][1] - K[1][1] * K[2][0]) * id;
    Ki[2][1] = (K[0][1] * K[2][0] - K[0][0] * K[2][1]) * id;
    Ki[2][2] = (K[0][0] * K[1][1] - K[0][1] * K[1][0]) * id;
    double A[3][3], bv[3];
#pragma unroll
    for (int r = 0; r < 3; ++r) {
#pragma unroll
        for (int c = 0; c < 3; ++c)
            A[r][c] = Ki[r][0] * R[0][c] + Ki[r][1] * R[1][c] + Ki[r][2] * R[2][c];
        bv[r] = Ki[r][0] * tv[0] + Ki[r][1] * tv[1] + Ki[r][2] * tv[2];
    }
    double* g = gc + n * 24;
#pragma unroll
    for (int r = 0; r < 3; ++r)
#pragma unroll
        for (int c = 0; c < 3; ++c) g[r * 3 + c] = A[r][c];
#pragma unroll
    for (int r = 0; r < 3; ++r) g[9 + r] = bv[r];
#pragma unroll
    for (int r = 0; r < 3; ++r)
#pragma unroll
        for (int c = 0; c < 4; ++c) {
            double acc = 0.0;
#pragma unroll
            for (int k = 0; k < 4; ++k)
                acc += (double)bda[r * 4 + k] * (double)s2e[n * 16 + k * 4 + c];
            g[12 + r * 4 + c] = acc;
        }
}

// ---------------- per-point voxel index + histogram (fused) ------------------
__global__ __launch_bounds__(256) void point_voxel_k(
    const double* __restrict__ gc, int* __restrict__ vidx, int* __restrict__ cnt)
{
    const int i = blockIdx.x * 256 + threadIdx.x;
    if (i >= NPTS) return;
    const int n = i / (DCH * SP_);
    int r = i - n * (DCH * SP_);
    const int di = r / SP_;
    const int s = r - di * SP_;
    const int h = s / FW_, w = s - h * FW_;
    const double* g = gc + n * 24;
    const double u  = (double)(float)((double)w * (703.0 / 43.0));
    const double v  = (double)(float)((double)h * 17.0);
    const double dd = (double)(float)(2.0 + (double)di * (56.0 / 111.0));
    const double rx = g[0] * u + g[1] * v + g[2] + g[9];
    const double ry = g[3] * u + g[4] * v + g[5] + g[10];
    const double rz = g[6] * u + g[7] * v + g[8] + g[11];
    const double px = rx * dd, py = ry * dd, pz = rz * dd;
    const double ex = g[12] * px + g[13] * py + g[14] * pz + g[15];
    const double ey = g[16] * px + g[17] * py + g[18] * pz + g[19];
    const double ez = g[20] * px + g[21] * py + g[22] * pz + g[23];
    const double vs_xy = 0.8, vs_z = 8.0;
    const double offx = (double)(float)(-51.2 + 0.4) - vs_xy * 0.5;
    const double offz = (double)(float)(-5.0 + 4.0) - vs_z * 0.5;
    const int gx = (int)((ex - offx) / vs_xy);
    const int gy = (int)((ey - offx) / vs_xy);
    const int gz = (int)((ez - offz) / vs_z);
    const bool ok = (gx >= 0 && gx < NXY && gy >= 0 && gy < NXY && gz == 0);
    const int vv = ok ? (gy * NXY + gx) : -1;
    vidx[i] = vv;
    if (vv >= 0) atomicAdd(&cnt[vv], 1);
}

// off has NVOX+1 entries; off[NVOX] = total valid points
__global__ void prefix_k(const int* __restrict__ cnt, int* __restrict__ off,
                         int* __restrict__ cur) {
    __shared__ int part[256];
    const int t = threadIdx.x;
    int s = 0;
    for (int j = 0; j < 64; ++j) s += cnt[t * 64 + j];
    part[t] = s;
    __syncthreads();
    if (t == 0) {
        int run = 0;
        for (int k = 0; k < 256; ++k) { int v = part[k]; part[k] = run; run += v; }
    }
    __syncthreads();
    int base = part[t];
    for (int j = 0; j < 64; ++j) {
        off[t * 64 + j] = base;
        cur[t * 64 + j] = base;
        base += cnt[t * 64 + j];
    }
    if (t == 255) off[NVOX] = base;
}

// fill packed entries: key = (v<<13) | (n*SP_+s), prob bits; prob [n][s][112]
__global__ void fill_k(const int* __restrict__ vidx, const float* __restrict__ prob,
                       int* __restrict__ cur, int2* __restrict__ pk) {
    int i = blockIdx.x * 256 + threadIdx.x;
    if (i >= NPTS) return;
    int v = vidx[i];
    if (v < 0) return;
    const int n = i / (DCH * SP_);
    int r = i - n * (DCH * SP_);
    const int di = r / SP_;
    const int s = r - di * SP_;
    int pos = atomicAdd(&cur[v], 1);
    pk[pos] = make_int2((v << 13) | (n * SP_ + s),
                        __float_as_int(prob[((size_t)n * SP_ + s) * DCH + di]));
}

// ---------------- gather: chunk-per-wave segmented reduction ------------------
__global__ __launch_bounds__(256) void gather2_k(
    const int2* __restrict__ pk, const int* __restrict__ off,
    const float* __restrict__ ctxT, float* __restrict__ accT)
{
    const int gtid = blockIdx.x * 256 + threadIdx.x;
    const int wid = gtid >> 6;
    const int lane = threadIdx.x & 63;
    const int total = off[NVOX];
    const int lo = wid * CHUNK;
    if (lo >= total) return;
    const int hi = min(lo + CHUNK, total);
    float a0 = 0.f, a1 = 0.f;
    int2 e = pk[lo];
    for (int k = lo; k < hi; ++k) {
        const int2 en = (k + 1 < hi) ? pk[k + 1] : make_int2(-1, 0);
        const float p = __int_as_float(e.y);
        const int ns = e.x & 8191;
        const float* cb = ctxT + (size_t)ns * CCTX;
        a0 = fmaf(p, cb[lane], a0);
        if (lane < CCTX - 64) a1 = fmaf(p, cb[64 + lane], a1);
        if ((en.x >> 13) != (e.x >> 13)) {         // wave-uniform flush
            float* ab = accT + (size_t)(e.x >> 13) * CCTX;
            atomicAdd(ab + lane, a0);
            if (lane < CCTX - 64) atomicAdd(ab + 64 + lane, a1);
            a0 = a1 = 0.f;
        }
        e = en;
    }
}

// ---------------- transpose accT [v][c] -> out [c][v] ------------------------
__global__ void transpose_out_k(const float* __restrict__ accT, float* __restrict__ out) {
    const int idx = blockIdx.x * 256 + threadIdx.x;
    if (idx >= CCTX * NVOX) return;
    const int c = idx >> 14;
    const int v = idx & 16383;
    out[idx] = accT[(size_t)v * CCTX + c];
}

// ---------------- workspace layout (float offsets) ---------------------------
#define O_WHIA  512           // bf16 conv weights A [9][512][512]: 1,179,648
#define O_WHIB  1180160       // bf16 conv weights B: 1,179,648
#define O_XT0   2359808       // 1,474,560
#define O_XT1   3834368       // 1,474,560
#define O_XT2   5308928       // 1,474,560
#define O_WD2B  6783488       // 28,672 (bf16 112x512)
#define O_WC2B  6812160       // 20,480 (bf16 80x512)
#define O_DLG   6832640       // 473,088  [n][s][112]
#define O_DPR   7305728       // 473,088
#define O_CTX   7778816       // 337,920  [n][s][80]
#define O_PK    8116736       // 946,176 (int2 x 473,088)
#define O_VIX   9062912       // 473,088
#define O_CNT   9536000       // 16,384
#define O_OFF   9552384       // 16,400
#define O_CUR   9568784       // 16,384
#define O_ACC   9585168       // 1,310,720
// end: 10,895,888 floats = 43.6 MB

extern "C" void kernel_launch(void* const* d_in, const int* in_sizes, int n_in,
                              void* d_out, int out_size, void* d_ws, size_t ws_size,
                              hipStream_t stream)
{
    const float* src  = (const float*)d_in[0];
    const float* w_s1 = (const float*)d_in[1];
    const float* w_s2 = (const float*)d_in[2];
    const float* w_d1 = (const float*)d_in[3];
    const float* w_d2 = (const float*)d_in[4];
    const float* b_d  = (const float*)d_in[5];
    const float* w_c1 = (const float*)d_in[6];
    const float* w_c2 = (const float*)d_in[7];
    const float* b_c  = (const float*)d_in[8];
    const float* s2e  = (const float*)d_in[9];
    const float* intr = (const float*)d_in[10];
    const float* ida  = (const float*)d_in[11];
    const float* bda  = (const float*)d_in[12];

    double* gc = (double*)d_ws;
    float* ws   = (float*)d_ws;
    short* whiA = (short*)(ws + O_WHIA);
    short* whiB = (short*)(ws + O_WHIB);
    short* xt0  = (short*)(ws + O_XT0);
    short* xt1  = (short*)(ws + O_XT1);
    short* xt2  = (short*)(ws + O_XT2);
    short* wd2b = (short*)(ws + O_WD2B);
    short* wc2b = (short*)(ws + O_WC2B);
    float* dlog = ws + O_DLG;
    float* dprb = ws + O_DPR;
    float* ctxT = ws + O_CTX;
    int2*  pk   = (int2*)(ws + O_PK);
    int* vidx   = (int*)(ws + O_VIX);
    int* cnt    = (int*)(ws + O_CNT);
    int* offs   = (int*)(ws + O_OFF);
    int* cur    = (int*)(ws + O_CUR);
    float* accT = ws + O_ACC;
    float* out  = (float*)d_out;

    // zero xt0+xt1 (contiguous; provides pad borders). xt2 rows fully written
    // by d1 before being read -> no zeroing needed.
    zero_k<<<(2949120 / 4 + 255) / 256, 256, 0, stream>>>((float4*)xt0, 2949120 / 4);

    geom_setup_k<<<1, 64, 0, stream>>>(s2e, intr, ida, bda, gc);
    src_to_xt_k<<<(NIMG * SP_ * CIN + 255) / 256, 256, 0, stream>>>(src, xt0);

    // s1: xt0 -> xt1
    wsplit_k<<<(CIN * CIN) / 256, 256, 0, stream>>>(w_s1, whiA);
    conv3s_k<<<TPL2, 128, 0, stream>>>(xt0, whiA, xt1, whiA, xt1, TPL2);
    // s2: xt1 -> xt0
    wsplit_k<<<(CIN * CIN) / 256, 256, 0, stream>>>(w_s2, whiA);
    conv3s_k<<<TPL2, 128, 0, stream>>>(xt1, whiA, xt0, whiA, xt0, TPL2);
    // d1 + c1 fused: xt0 -> xt2 (depth branch), xt0 -> xt1 (context branch)
    wsplit_dual_k<<<(2 * CIN * CIN) / 256, 256, 0, stream>>>(w_d1, whiA, w_c1, whiB);
    conv3s_k<<<2 * TPL2, 128, 0, stream>>>(xt0, whiA, xt2, whiB, xt1, 2 * TPL2);

    // 1x1 weights (both) in one dispatch
    wsplit1_dual_k<<<((DCH + CCTX) * CIN + 255) / 256, 256, 0, stream>>>(w_d2, wd2b, w_c2, wc2b);
    // merged d2 + c2 gemms: xt2 -> dlog [n][s][112], xt1 -> ctxT [n][s][80]
    gemm1x1d_k<<<dim3(6, 2, NIMG), 256, 0, stream>>>(xt2, wd2b, b_d, dlog,
                                                     xt1, wc2b, b_c, ctxT);
    softmax2_k<<<(NIMG * SP_ + 3) / 4, 256, 0, stream>>>(dlog, dprb);

    // binning
    zero_k<<<(NVOX / 4 + 255) / 256, 256, 0, stream>>>((float4*)cnt, NVOX / 4);
    point_voxel_k<<<(NPTS + 255) / 256, 256, 0, stream>>>(gc, vidx, cnt);
    prefix_k<<<1, 256, 0, stream>>>(cnt, offs, cur);
    fill_k<<<(NPTS + 255) / 256, 256, 0, stream>>>(vidx, dprb, cur, pk);

    // segmented-reduction gather
    zero_k<<<(1310720 / 4 + 255) / 256, 256, 0, stream>>>((float4*)accT, 1310720 / 4);
    {
        const int waves = (NPTS + CHUNK - 1) / CHUNK;
        const int blocks = (waves + 3) / 4;
        gather2_k<<<blocks, 256, 0, stream>>>(pk, offs, ctxT, accT);
    }
    transpose_out_k<<<(CCTX * NVOX + 255) / 256, 256, 0, stream>>>(accT, out);

    (void)in_sizes; (void)n_in; (void)out_size; (void)ws_size;
}

// Round 3
// 502.530 us; speedup vs baseline: 1.2026x; 1.2026x over previous
//
#include <hip/hip_runtime.h>

// LSS-FPN round 13: conv as 4 identical K-split dispatches.
// Block = 256 thr = 4 waves (2M x 2N), tile 128sp x 128co, ci half per block
// (K-split x2 across blocks -> fp32 partials + combine). Register-prefetch
// pipeline: kc+1 staging loads issued before kc compute (T14); LDS single-
// buffered 66.4 KB -> 2 blocks/CU = 8 waves/CU. XCD swizzle: bid&7 =
// (half*4+co_blk) pins each 590 KB W slice to one XCD (L2-resident).
// Partials: 12 chunks of 704*512 fp32 in dead whiB region + post-conv tail.
// Tail (gemm1x1d / softmax2 / binning / gather) unchanged from R12.

#define FH_ 16
#define FW_ 44
#define SP_ 704
#define XSTR 960         // xt rows per image (incl. halo slack)
#define NIMG 6
#define CIN 512
#define DCH 112
#define CCTX 80
#define NXY 128
#define NVOX (NXY * NXY)
#define NPTS (NIMG * DCH * SP_)
#define CHUNK 64

#define WROWS 232        // LDS X window rows (128-px tile + 3x3 halo)
#define XP 24            // LDS row stride in shorts (48 B, bank-floor)
#define NKC 16           // kc steps per block (16 ci each; half of K)
#define CHK 360448       // partial chunk: 704*512 floats
#define CIP 40           // padded LDS k-stride for gemm1x1 (shorts)

typedef unsigned short u16;
typedef __attribute__((ext_vector_type(8))) short bf16x8;
typedef __attribute__((ext_vector_type(4))) short s16x4;
typedef __attribute__((ext_vector_type(4))) float f32x4;
typedef __attribute__((ext_vector_type(16))) float f32x16;

__device__ __forceinline__ float bf2f(u16 b) {
    union { unsigned u; float f; } v; v.u = ((unsigned)b) << 16; return v.f;
}
__device__ __forceinline__ u16 f2bf(float f) {
    union { float f; unsigned u; } v; v.f = f;
    unsigned r = v.u + 0x7fffu + ((v.u >> 16) & 1u);   // RTNE
    return (u16)(r >> 16);
}
__device__ __forceinline__ int spad_of(int s) {
    return (s / 44) * 46 + (s % 44) + 47;
}
// partial chunk c = half*6+n: first 3 chunks in dead whiB region (pA),
// rest in post-conv tail region (pB).
__device__ __forceinline__ float* chunkp(float* pA, float* pB, int h, int n) {
    int c = h * 6 + n;
    return (c < 3) ? (pA + (size_t)c * CHK) : (pB + (size_t)(c - 3) * CHK);
}

// ---------------- zero fill ---------------------------------------------------
__global__ void zero_k(float4* __restrict__ p, long n4) {
    long i = (long)blockIdx.x * blockDim.x + threadIdx.x;
    if (i < n4) p[i] = make_float4(0.f, 0.f, 0.f, 0.f);
}

// ---------------- src fp32 [n][ci][704] -> xt bf16 [n][XSTR][512] -------------
__global__ void src_to_xt_k(const float* __restrict__ src, short* __restrict__ xt) {
    int e = blockIdx.x * 256 + threadIdx.x;
    if (e >= NIMG * SP_ * CIN) return;
    int ci = e & 511;
    int r = e >> 9;
    int s = r % SP_, n = r / SP_;
    float v = src[((size_t)n * CIN + ci) * SP_ + s];
    xt[((size_t)n * XSTR + spad_of(s)) * 512 + ci] = (short)f2bf(v);
}

// ---------------- weight convert: fp32 [co][ci][9] -> bf16 [t][co][ci] --------
__global__ void wsplit_k(const float* __restrict__ w, short* __restrict__ hi) {
    int e = blockIdx.x * 256 + threadIdx.x;
    if (e >= CIN * CIN) return;
    const float* wp = w + (size_t)e * 9;
#pragma unroll
    for (int t = 0; t < 9; ++t)
        hi[(size_t)t * (CIN * CIN) + e] = (short)f2bf(wp[t]);
}

// dual 1x1 weights fp32 [co][ci] -> bf16
__global__ void wsplit1_dual_k(const float* __restrict__ wd, short* __restrict__ od,
                               const float* __restrict__ wc, short* __restrict__ oc) {
    int i = blockIdx.x * 256 + threadIdx.x;
    if (i < DCH * CIN) od[i] = (short)f2bf(wd[i]);
    else if (i < DCH * CIN + CCTX * CIN) {
        int j = i - DCH * CIN;
        oc[j] = (short)f2bf(wc[j]);
    }
}

// ---------------- conv3x3, K-split, reg-prefetch pipeline --------------------
// grid 288: bid = rest*8 + (half*4 + cb); rest = n*6 + sb.
// Block tile 128sp x 128co over 256 ci (half). 4 waves (mw,nw) each 64x64.
// Output: fp32 partial to chunk(half, n), layout [s][co].
__global__ __launch_bounds__(256, 2) void conv4_k(
    const short* __restrict__ xt, const short* __restrict__ whi,
    float* __restrict__ pA, float* __restrict__ pB)
{
    __shared__ short Xs[WROWS * XP];       // 11,136 B
    __shared__ short Wsh[1152 * XP];       // 55,296 B
    const int tid = threadIdx.x;
    const int lane = tid & 63, wave = tid >> 6;
    const int l31 = lane & 31, lh = lane >> 5;
    const int mw = wave >> 1, nw = wave & 1;

    const int bid = blockIdx.x;
    const int cb = bid & 3;
    const int half = (bid >> 2) & 1;
    const int rest = bid >> 3;
    const int n = rest / 6, sb = rest - (rest / 6) * 6;

    const int s0 = sb * 128;
    const int co0 = cb * 128;
    const int base = spad_of(s0) - 47;
    const short* __restrict__ xb = xt + ((size_t)n * XSTR + base) * 512 + half * 256;
    const short* __restrict__ wb = whi + half * 256;

    int sloc[2];
#pragma unroll
    for (int mf = 0; mf < 2; ++mf)
        sloc[mf] = spad_of(s0 + mw * 64 + mf * 32 + l31) - base;

    // staging task map (constant per thread)
    const int xq0 = tid, xq1 = 256 + tid;
    const bool x2 = (tid < WROWS * 2 - 256);          // tid < 208

    const f32x16 z16 = {0.f,0.f,0.f,0.f,0.f,0.f,0.f,0.f,
                        0.f,0.f,0.f,0.f,0.f,0.f,0.f,0.f};
    f32x16 acc[2][2];
    acc[0][0] = z16; acc[0][1] = z16; acc[1][0] = z16; acc[1][1] = z16;

    bf16x8 rx0, rx1, rw[9];

#define CLOAD(KO) do {                                                          \
    rx0 = *(const bf16x8*)(xb + (size_t)(xq0 >> 1) * 512 + (KO) + (xq0 & 1) * 8); \
    if (x2)                                                                     \
        rx1 = *(const bf16x8*)(xb + (size_t)(xq1 >> 1) * 512 + (KO) + (xq1 & 1) * 8); \
    _Pragma("unroll")                                                           \
    for (int w = 0; w < 9; ++w) {                                               \
        int q = w * 256 + tid; int wr = q >> 1;                                 \
        rw[w] = *(const bf16x8*)(wb + ((size_t)(wr >> 7) * CIN + co0 + (wr & 127)) * CIN \
                                 + (KO) + (q & 1) * 8);                         \
    }                                                                           \
} while (0)

#define CSTORE() do {                                                           \
    *(bf16x8*)&Xs[(xq0 >> 1) * XP + (xq0 & 1) * 8] = rx0;                       \
    if (x2) *(bf16x8*)&Xs[(xq1 >> 1) * XP + (xq1 & 1) * 8] = rx1;               \
    _Pragma("unroll")                                                           \
    for (int w = 0; w < 9; ++w) {                                               \
        int q = w * 256 + tid;                                                  \
        *(bf16x8*)&Wsh[(q >> 1) * XP + (q & 1) * 8] = rw[w];                    \
    }                                                                           \
} while (0)

    CLOAD(0);
    CSTORE();
    __syncthreads();

    constexpr int OFF[9] = {-47, -46, -45, -1, 0, 1, 45, 46, 47};
    for (int kc = 0; kc < NKC; ++kc) {
        if (kc + 1 < NKC) CLOAD((kc + 1) * 16);
#pragma unroll
        for (int t9 = 0; t9 < 9; ++t9) {
            const int off = OFF[t9];
            bf16x8 a0 = *(const bf16x8*)&Xs[(sloc[0] + off) * XP + lh * 8];
            bf16x8 a1 = *(const bf16x8*)&Xs[(sloc[1] + off) * XP + lh * 8];
            bf16x8 b0 = *(const bf16x8*)&Wsh[(t9 * 128 + nw * 64 + l31) * XP + lh * 8];
            bf16x8 b1 = *(const bf16x8*)&Wsh[(t9 * 128 + nw * 64 + 32 + l31) * XP + lh * 8];
            acc[0][0] = __builtin_amdgcn_mfma_f32_32x32x16_bf16(a0, b0, acc[0][0], 0, 0, 0);
            acc[0][1] = __builtin_amdgcn_mfma_f32_32x32x16_bf16(a0, b1, acc[0][1], 0, 0, 0);
            acc[1][0] = __builtin_amdgcn_mfma_f32_32x32x16_bf16(a1, b0, acc[1][0], 0, 0, 0);
            acc[1][1] = __builtin_amdgcn_mfma_f32_32x32x16_bf16(a1, b1, acc[1][1], 0, 0, 0);
        }
        __syncthreads();                 // all waves done reading LDS
        if (kc + 1 < NKC) CSTORE();      // dump prefetched regs
        __syncthreads();                 // writes visible
    }
#undef CLOAD
#undef CSTORE

    // epilogue: fp32 partial store; C row = (r&3)+8*(r>>2)+4*lh, col = l31
    float* __restrict__ Pc = chunkp(pA, pB, half, n);
#pragma unroll
    for (int mf = 0; mf < 2; ++mf) {
        const int spb = mw * 64 + mf * 32 + 4 * lh;
#pragma unroll
        for (int r = 0; r < 16; ++r) {
            const int sg = s0 + spb + (r & 3) + 8 * (r >> 2);
            if (sg < SP_) {
                const size_t ro = (size_t)sg * 512 + co0 + nw * 64 + l31;
                Pc[ro] = acc[mf][0][r];
                Pc[ro + 32] = acc[mf][1][r];
            }
        }
    }
}

// ---------------- combine: relu(P0+P1) -> bf16 padded xt ----------------------
__global__ __launch_bounds__(256) void combine_k(
    float* __restrict__ pA, float* __restrict__ pB, short* __restrict__ xout)
{
    const int i = blockIdx.x * 256 + threadIdx.x;
    if (i >= NIMG * SP_ * CIN / 4) return;
    const int e = i * 4;
    const int n = e / (SP_ * CIN);
    const int r = e - n * (SP_ * CIN);
    const int s = r >> 9, co = r & 511;
    const float* c0 = chunkp(pA, pB, 0, n);
    const float* c1 = chunkp(pA, pB, 1, n);
    const float4 a = *(const float4*)(c0 + r);
    const float4 b = *(const float4*)(c1 + r);
    s16x4 o;
    o[0] = (short)f2bf(fmaxf(a.x + b.x, 0.f));
    o[1] = (short)f2bf(fmaxf(a.y + b.y, 0.f));
    o[2] = (short)f2bf(fmaxf(a.z + b.z, 0.f));
    o[3] = (short)f2bf(fmaxf(a.w + b.w, 0.f));
    *(s16x4*)&xout[((size_t)n * XSTR + spad_of(s)) * 512 + co] = o;
}

// ---------------- merged 1x1 convs (d2 + c2) as GEMM -------------------------
// grid (6, 2, 6): y=0 -> depth head (NCO=112), y=1 -> context head (NCO=80).
__global__ __launch_bounds__(256, 2) void gemm1x1d_k(
    const short* __restrict__ xA, const short* __restrict__ wA,
    const float* __restrict__ bA, float* __restrict__ oA,
    const short* __restrict__ xB, const short* __restrict__ wB,
    const float* __restrict__ bB, float* __restrict__ oB)
{
    const int sel = blockIdx.y;
    const short* __restrict__ xtin = sel ? xB : xA;
    const short* __restrict__ wb   = sel ? wB : wA;
    const float* __restrict__ bias = sel ? bB : bA;
    float* __restrict__ outT       = sel ? oB : oA;
    const int nst = sel ? (CCTX / 16) : (DCH / 16);   // 5 or 7
    const int nco = nst * 16;

    __shared__ short Wb[DCH * CIP];
    const int tid = threadIdx.x;
    const int s0 = blockIdx.x * 128, n = blockIdx.z;
    const int lane = tid & 63, wave = tid >> 6;
    const int kg = lane >> 4, lrow = lane & 15;
    const int swave = s0 + wave * 32;

    int arow[2];
#pragma unroll
    for (int ms = 0; ms < 2; ++ms)
        arow[ms] = spad_of(swave + ms * 16 + lrow);

    const f32x4 zero4 = {0.f, 0.f, 0.f, 0.f};
    f32x4 acc[2][7];
#pragma unroll
    for (int ms = 0; ms < 2; ++ms)
#pragma unroll
        for (int ns = 0; ns < 7; ++ns) acc[ms][ns] = zero4;

    const short* xb = xtin + (size_t)n * XSTR * 512;

    for (int kc = 0; kc < 16; ++kc) {
        __syncthreads();
#pragma unroll
        for (int it = 0; it < 2; ++it) {
            int q = it * 256 + tid;
            if (q < nco * 4) {
                int co = q >> 2, p = q & 3;
                *(bf16x8*)&Wb[co * CIP + p * 8] =
                    *(const bf16x8*)(wb + (size_t)co * CIN + kc * 32 + p * 8);
            }
        }
        __syncthreads();
        bf16x8 a[2];
#pragma unroll
        for (int ms = 0; ms < 2; ++ms)
            a[ms] = *(const bf16x8*)(xb + (size_t)arow[ms] * 512 + kc * 32 + kg * 8);
#pragma unroll
        for (int ns = 0; ns < 7; ++ns) {
            if (ns < nst) {
                int co = ns * 16 + lrow;
                bf16x8 b = *(const bf16x8*)&Wb[co * CIP + kg * 8];
#pragma unroll
                for (int ms = 0; ms < 2; ++ms)
                    acc[ms][ns] = __builtin_amdgcn_mfma_f32_16x16x32_bf16(
                        a[ms], b, acc[ms][ns], 0, 0, 0);
            }
        }
    }
#pragma unroll
    for (int ms = 0; ms < 2; ++ms)
#pragma unroll
        for (int ns = 0; ns < 7; ++ns) {
            if (ns < nst) {
#pragma unroll
                for (int r = 0; r < 4; ++r) {
                    int sg = swave + ms * 16 + kg * 4 + r;
                    if (sg < SP_) {
                        int co = ns * 16 + lrow;
                        outT[((size_t)n * SP_ + sg) * nco + co] = acc[ms][ns][r] + bias[co];
                    }
                }
            }
        }
}

// ---------------- softmax over d, layout [n][s][112] (d contiguous) ----------
__global__ __launch_bounds__(256) void softmax2_k(
    const float* __restrict__ lg, float* __restrict__ pr)
{
    const int p = blockIdx.x * 4 + (threadIdx.x >> 6);
    if (p >= NIMG * SP_) return;
    const int lane = threadIdx.x & 63;
    const float* lp = lg + (size_t)p * DCH;
    float v0 = lp[lane];
    float v1 = (lane < DCH - 64) ? lp[64 + lane] : -1e30f;
    float m = fmaxf(v0, v1);
#pragma unroll
    for (int o = 32; o; o >>= 1) m = fmaxf(m, __shfl_xor(m, o));
    float e0 = __expf(v0 - m);
    float e1 = (lane < DCH - 64) ? __expf(v1 - m) : 0.f;
    float s = e0 + e1;
#pragma unroll
    for (int o = 32; o; o >>= 1) s += __shfl_xor(s, o);
    const float inv = 1.f / s;
    float* pp = pr + (size_t)p * DCH;
    pp[lane] = e0 * inv;
    if (lane < DCH - 64) pp[64 + lane] = e1 * inv;
}

// ---------------- per-camera geometry constants (fp64, closed-form) ----------
__device__ __forceinline__ void inv4(const double* M, double* inv) {
    inv[0]  =  M[5]*M[10]*M[15] - M[5]*M[11]*M[14] - M[9]*M[6]*M[15] + M[9]*M[7]*M[14] + M[13]*M[6]*M[11] - M[13]*M[7]*M[10];
    inv[4]  = -M[4]*M[10]*M[15] + M[4]*M[11]*M[14] + M[8]*M[6]*M[15] - M[8]*M[7]*M[14] - M[12]*M[6]*M[11] + M[12]*M[7]*M[10];
    inv[8]  =  M[4]*M[9]*M[15]  - M[4]*M[11]*M[13] - M[8]*M[5]*M[15] + M[8]*M[7]*M[13] + M[12]*M[5]*M[11] - M[12]*M[7]*M[9];
    inv[12] = -M[4]*M[9]*M[14]  + M[4]*M[10]*M[13] + M[8]*M[5]*M[14] - M[8]*M[6]*M[13] - M[12]*M[5]*M[10] + M[12]*M[6]*M[9];
    inv[1]  = -M[1]*M[10]*M[15] + M[1]*M[11]*M[14] + M[9]*M[2]*M[15] - M[9]*M[3]*M[14] - M[13]*M[2]*M[11] + M[13]*M[3]*M[10];
    inv[5]  =  M[0]*M[10]*M[15] - M[0]*M[11]*M[14] - M[8]*M[2]*M[15] + M[8]*M[3]*M[14] + M[12]*M[2]*M[11] - M[12]*M[3]*M[10];
    inv[9]  = -M[0]*M[9]*M[15]  + M[0]*M[11]*M[13] + M[8]*M[1]*M[15] - M[8]*M[3]*M[13] - M[12]*M[1]*M[11] + M[12]*M[3]*M[9];
    inv[13] =  M[0]*M[9]*M[14]  - M[0]*M[10]*M[13] - M[8]*M[1]*M[14] + M[8]*M[2]*M[13] + M[12]*M[1]*M[10] - M[12]*M[2]*M[9];
    inv[2]  =  M[1]*M[6]*M[15]  - M[1]*M[7]*M[14]  - M[5]*M[2]*M[15] + M[5]*M[3]*M[14] + M[13]*M[2]*M[7]  - M[13]*M[3]*M[6];
    inv[6]  = -M[0]*M[6]*M[15]  + M[0]*M[7]*M[14]  + M[4]*M[2]*M[15] - M[4]*M[3]*M[14] - M[12]*M[2]*M[7]  + M[12]*M[3]*M[6];
    inv[10] =  M[0]*M[5]*M[15]  - M[0]*M[7]*M[13]  - M[4]*M[1]*M[15] + M[4]*M[3]*M[13] + M[12]*M[1]*M[7]  - M[12]*M[3]*M[5];
    inv[14] = -M[0]*M[5]*M[14]  + M[0]*M[6]*M[13]  + M[4]*M[1]*M[14] - M[4]*M[2]*M[13] - M[12]*M[1]*M[6]  + M[12]*M[2]*M[5];
    inv[3]  = -M[1]*M[6]*M[11]  + M[1]*M[7]*M[10]  + M[5]*M[2]*M[11] - M[5]*M[3]*M[10] - M[9]*M[2]*M[7]   + M[9]*M[3]*M[6];
    inv[7]  =  M[0]*M[6]*M[11]  - M[0]*M[7]*M[10]  - M[4]*M[2]*M[11] + M[4]*M[3]*M[10] + M[8]*M[2]*M[7]   - M[8]*M[3]*M[6];
    inv[11] = -M[0]*M[5]*M[11]  + M[0]*M[7]*M[9]   + M[4]*M[1]*M[11] - M[4]*M[3]*M[9]  - M[8]*M[1]*M[7]   + M[8]*M[3]*M[5];
    inv[15] =  M[0]*M[5]*M[10]  - M[0]*M[6]*M[9]   - M[4]*M[1]*M[10] + M[4]*M[2]*M[9]  + M[8]*M[1]*M[6]   - M[8]*M[2]*M[5];
    double det = M[0]*inv[0] + M[1]*inv[4] + M[2]*inv[8] + M[3]*inv[12];
    double id = 1.0 / det;
#pragma unroll
    for (int i = 0; i < 16; ++i) inv[i] *= id;
}

__global__ void geom_setup_k(const float* __restrict__ s2e, const float* __restrict__ intrin,
                             const float* __restrict__ ida, const float* __restrict__ bda,
                             double* __restrict__ gc)
{
    const int n = threadIdx.x;
    if (n >= NIMG) return;
    double M[16], Iv[16];
#pragma unroll
    for (int i = 0; i < 16; ++i) M[i] = (double)ida[n * 16 + i];
    inv4(M, Iv);
    double R[3][3], tv[3];
#pragma unroll
    for (int r = 0; r < 3; ++r) {
#pragma unroll
        for (int c = 0; c < 3; ++c) R[r][c] = Iv[r * 4 + c];
        tv[r] = Iv[r * 4 + 3];
    }
    double K[3][3];
#pragma unroll
    for (int r = 0; r < 3; ++r)
#pragma unroll
        for (int c = 0; c < 3; ++c) K[r][c] = (double)intrin[n * 16 + r * 4 + c];
    double det = K[0][0] * (K[1][1] * K[2][2] - K[1][2] * K[2][1])
               - K[0][1] * (K[1][0] * K[2][2] - K[1][2] * K[2][0])
               + K[0][2] * (K[1][0] * K[2][1] - K[1][1] * K[2][0]);
    double id = 1.0 / det;
    double Ki[3][3];
    Ki[0][0] = (K[1][1] * K[2][2] - K[1][2] * K[2][1]) * id;
    Ki[0][1] = (K[0][2] * K[2][1] - K[0][1] * K[2][2]) * id;
    Ki[0][2] = (K[0][1] * K[1][2] - K[0][2] * K[1][1]) * id;
    Ki[1][0] = (K[1][2] * K[2][0] - K[1][0] * K[2][2]) * id;
    Ki[1][1] = (K[0][0] * K[2][2] - K[0][2] * K[2][0]) * id;
    Ki[1][2] = (K[0][2] * K[1][0] - K[0][0] * K[1][2]) * id;
    Ki[2][0] = (K[1][0] * K[2][1] - K[1][1] * K[2][0]) * id;
    Ki[2][1] = (K[0][1] * K[2][0] - K[0][0] * K[2][1]) * id;
    Ki[2][2] = (K[0][0] * K[1][1] - K[0][1] * K[1][0]) * id;
    double A[3][3], bv[3];
#pragma unroll
    for (int r = 0; r < 3; ++r) {
#pragma unroll
        for (int c = 0; c < 3; ++c)
            A[r][c] = Ki[r][0] * R[0][c] + Ki[r][1] * R[1][c] + Ki[r][2] * R[2][c];
        bv[r] = Ki[r][0] * tv[0] + Ki[r][1] * tv[1] + Ki[r][2] * tv[2];
    }
    double* g = gc + n * 24;
#pragma unroll
    for (int r = 0; r < 3; ++r)
#pragma unroll
        for (int c = 0; c < 3; ++c) g[r * 3 + c] = A[r][c];
#pragma unroll
    for (int r = 0; r < 3; ++r) g[9 + r] = bv[r];
#pragma unroll
    for (int r = 0; r < 3; ++r)
#pragma unroll
        for (int c = 0; c < 4; ++c) {
            double acc = 0.0;
#pragma unroll
            for (int k = 0; k < 4; ++k)
                acc += (double)bda[r * 4 + k] * (double)s2e[n * 16 + k * 4 + c];
            g[12 + r * 4 + c] = acc;
        }
}

// ---------------- per-point voxel index + histogram (fused) ------------------
__global__ __launch_bounds__(256) void point_voxel_k(
    const double* __restrict__ gc, int* __restrict__ vidx, int* __restrict__ cnt)
{
    const int i = blockIdx.x * 256 + threadIdx.x;
    if (i >= NPTS) return;
    const int n = i / (DCH * SP_);
    int r = i - n * (DCH * SP_);
    const int di = r / SP_;
    const int s = r - di * SP_;
    const int h = s / FW_, w = s - h * FW_;
    const double* g = gc + n * 24;
    const double u  = (double)(float)((double)w * (703.0 / 43.0));
    const double v  = (double)(float)((double)h * 17.0);
    const double dd = (double)(float)(2.0 + (double)di * (56.0 / 111.0));
    const double rx = g[0] * u + g[1] * v + g[2] + g[9];
    const double ry = g[3] * u + g[4] * v + g[5] + g[10];
    const double rz = g[6] * u + g[7] * v + g[8] + g[11];
    const double px = rx * dd, py = ry * dd, pz = rz * dd;
    const double ex = g[12] * px + g[13] * py + g[14] * pz + g[15];
    const double ey = g[16] * px + g[17] * py + g[18] * pz + g[19];
    const double ez = g[20] * px + g[21] * py + g[22] * pz + g[23];
    const double vs_xy = 0.8, vs_z = 8.0;
    const double offx = (double)(float)(-51.2 + 0.4) - vs_xy * 0.5;
    const double offz = (double)(float)(-5.0 + 4.0) - vs_z * 0.5;
    const int gx = (int)((ex - offx) / vs_xy);
    const int gy = (int)((ey - offx) / vs_xy);
    const int gz = (int)((ez - offz) / vs_z);
    const bool ok = (gx >= 0 && gx < NXY && gy >= 0 && gy < NXY && gz == 0);
    const int vv = ok ? (gy * NXY + gx) : -1;
    vidx[i] = vv;
    if (vv >= 0) atomicAdd(&cnt[vv], 1);
}

// off has NVOX+1 entries; off[NVOX] = total valid points
__global__ void prefix_k(const int* __restrict__ cnt, int* __restrict__ off,
                         int* __restrict__ cur) {
    __shared__ int part[256];
    const int t = threadIdx.x;
    int s = 0;
    for (int j = 0; j < 64; ++j) s += cnt[t * 64 + j];
    part[t] = s;
    __syncthreads();
    if (t == 0) {
        int run = 0;
        for (int k = 0; k < 256; ++k) { int v = part[k]; part[k] = run; run += v; }
    }
    __syncthreads();
    int base = part[t];
    for (int j = 0; j < 64; ++j) {
        off[t * 64 + j] = base;
        cur[t * 64 + j] = base;
        base += cnt[t * 64 + j];
    }
    if (t == 255) off[NVOX] = base;
}

// fill packed entries: key = (v<<13) | (n*SP_+s), prob bits; prob [n][s][112]
__global__ void fill_k(const int* __restrict__ vidx, const float* __restrict__ prob,
                       int* __restrict__ cur, int2* __restrict__ pk) {
    int i = blockIdx.x * 256 + threadIdx.x;
    if (i >= NPTS) return;
    int v = vidx[i];
    if (v < 0) return;
    const int n = i / (DCH * SP_);
    int r = i - n * (DCH * SP_);
    const int di = r / SP_;
    const int s = r - di * SP_;
    int pos = atomicAdd(&cur[v], 1);
    pk[pos] = make_int2((v << 13) | (n * SP_ + s),
                        __float_as_int(prob[((size_t)n * SP_ + s) * DCH + di]));
}

// ---------------- gather: chunk-per-wave segmented reduction ------------------
__global__ __launch_bounds__(256) void gather2_k(
    const int2* __restrict__ pk, const int* __restrict__ off,
    const float* __restrict__ ctxT, float* __restrict__ accT)
{
    const int gtid = blockIdx.x * 256 + threadIdx.x;
    const int wid = gtid >> 6;
    const int lane = threadIdx.x & 63;
    const int total = off[NVOX];
    const int lo = wid * CHUNK;
    if (lo >= total) return;
    const int hi = min(lo + CHUNK, total);
    float a0 = 0.f, a1 = 0.f;
    int2 e = pk[lo];
    for (int k = lo; k < hi; ++k) {
        const int2 en = (k + 1 < hi) ? pk[k + 1] : make_int2(-1, 0);
        const float p = __int_as_float(e.y);
        const int ns = e.x & 8191;
        const float* cb = ctxT + (size_t)ns * CCTX;
        a0 = fmaf(p, cb[lane], a0);
        if (lane < CCTX - 64) a1 = fmaf(p, cb[64 + lane], a1);
        if ((en.x >> 13) != (e.x >> 13)) {         // wave-uniform flush
            float* ab = accT + (size_t)(e.x >> 13) * CCTX;
            atomicAdd(ab + lane, a0);
            if (lane < CCTX - 64) atomicAdd(ab + 64 + lane, a1);
            a0 = a1 = 0.f;
        }
        e = en;
    }
}

// ---------------- transpose accT [v][c] -> out [c][v] ------------------------
__global__ void transpose_out_k(const float* __restrict__ accT, float* __restrict__ out) {
    const int idx = blockIdx.x * 256 + threadIdx.x;
    if (idx >= CCTX * NVOX) return;
    const int c = idx >> 14;
    const int v = idx & 16383;
    out[idx] = accT[(size_t)v * CCTX + c];
}

// ---------------- workspace layout (float offsets) ---------------------------
#define O_WHIA  512           // bf16 conv weights [9][512][512]: 1,179,648 fl
#define O_WHIB  1180160       // partial chunks 0-2 (3 x 360,448 fp32)
#define O_XT0   2359808       // 1,474,560
#define O_XT1   3834368       // 1,474,560
#define O_XT2   5308928       // 1,474,560
#define O_WD2B  6783488       // partial chunks 3-11 during conv; then 1x1 wts
#define O_WC2B  6812160       // 20,480 (bf16 80x512)
#define O_DLG   6832640       // 473,088  [n][s][112]
#define O_DPR   7305728       // 473,088
#define O_CTX   7778816       // 337,920  [n][s][80]
#define O_PK    8116736       // 946,176 (int2 x 473,088)
#define O_VIX   9062912       // 473,088
#define O_CNT   9536000       // 16,384
#define O_OFF   9552384       // 16,400
#define O_CUR   9568784       // 16,384
#define O_ACC   9585168       // 1,310,720
// end: 10,895,888 floats = 43.6 MB (unchanged)

extern "C" void kernel_launch(void* const* d_in, const int* in_sizes, int n_in,
                              void* d_out, int out_size, void* d_ws, size_t ws_size,
                              hipStream_t stream)
{
    const float* src  = (const float*)d_in[0];
    const float* w_s1 = (const float*)d_in[1];
    const float* w_s2 = (const float*)d_in[2];
    const float* w_d1 = (const float*)d_in[3];
    const float* w_d2 = (const float*)d_in[4];
    const float* b_d  = (const float*)d_in[5];
    const float* w_c1 = (const float*)d_in[6];
    const float* w_c2 = (const float*)d_in[7];
    const float* b_c  = (const float*)d_in[8];
    const float* s2e  = (const float*)d_in[9];
    const float* intr = (const float*)d_in[10];
    const float* ida  = (const float*)d_in[11];
    const float* bda  = (const float*)d_in[12];

    double* gc = (double*)d_ws;
    float* ws   = (float*)d_ws;
    short* whiA = (short*)(ws + O_WHIA);
    float* pA   = ws + O_WHIB;           // chunks 0-2
    float* pB   = ws + O_WD2B;           // chunks 3-11
    short* xt0  = (short*)(ws + O_XT0);
    short* xt1  = (short*)(ws + O_XT1);
    short* xt2  = (short*)(ws + O_XT2);
    short* wd2b = (short*)(ws + O_WD2B);
    short* wc2b = (short*)(ws + O_WC2B);
    float* dlog = ws + O_DLG;
    float* dprb = ws + O_DPR;
    float* ctxT = ws + O_CTX;
    int2*  pk   = (int2*)(ws + O_PK);
    int* vidx   = (int*)(ws + O_VIX);
    int* cnt    = (int*)(ws + O_CNT);
    int* offs   = (int*)(ws + O_OFF);
    int* cur    = (int*)(ws + O_CUR);
    float* accT = ws + O_ACC;
    float* out  = (float*)d_out;

    const int CMB = (NIMG * SP_ * CIN / 4 + 255) / 256;   // 2112 blocks

    // zero xt0+xt1 (contiguous; provides pad borders). xt2 rows fully written
    // by d1-combine before being read -> no zeroing needed.
    zero_k<<<(2949120 / 4 + 255) / 256, 256, 0, stream>>>((float4*)xt0, 2949120 / 4);

    geom_setup_k<<<1, 64, 0, stream>>>(s2e, intr, ida, bda, gc);
    src_to_xt_k<<<(NIMG * SP_ * CIN + 255) / 256, 256, 0, stream>>>(src, xt0);

    // s1: xt0 -> xt1
    wsplit_k<<<(CIN * CIN) / 256, 256, 0, stream>>>(w_s1, whiA);
    conv4_k<<<288, 256, 0, stream>>>(xt0, whiA, pA, pB);
    combine_k<<<CMB, 256, 0, stream>>>(pA, pB, xt1);
    // s2: xt1 -> xt0
    wsplit_k<<<(CIN * CIN) / 256, 256, 0, stream>>>(w_s2, whiA);
    conv4_k<<<288, 256, 0, stream>>>(xt1, whiA, pA, pB);
    combine_k<<<CMB, 256, 0, stream>>>(pA, pB, xt0);
    // c1: xt0 -> xt1 (context branch)
    wsplit_k<<<(CIN * CIN) / 256, 256, 0, stream>>>(w_c1, whiA);
    conv4_k<<<288, 256, 0, stream>>>(xt0, whiA, pA, pB);
    combine_k<<<CMB, 256, 0, stream>>>(pA, pB, xt1);
    // d1: xt0 -> xt2 (depth branch)
    wsplit_k<<<(CIN * CIN) / 256, 256, 0, stream>>>(w_d1, whiA);
    conv4_k<<<288, 256, 0, stream>>>(xt0, whiA, pA, pB);
    combine_k<<<CMB, 256, 0, stream>>>(pA, pB, xt2);

    // 1x1 weights (both) in one dispatch -- AFTER convs (pB overlap)
    wsplit1_dual_k<<<((DCH + CCTX) * CIN + 255) / 256, 256, 0, stream>>>(w_d2, wd2b, w_c2, wc2b);
    // merged d2 + c2 gemms: xt2 -> dlog [n][s][112], xt1 -> ctxT [n][s][80]
    gemm1x1d_k<<<dim3(6, 2, NIMG), 256, 0, stream>>>(xt2, wd2b, b_d, dlog,
                                                     xt1, wc2b, b_c, ctxT);
    softmax2_k<<<(NIMG * SP_ + 3) / 4, 256, 0, stream>>>(dlog, dprb);

    // binning
    zero_k<<<(NVOX / 4 + 255) / 256, 256, 0, stream>>>((float4*)cnt, NVOX / 4);
    point_voxel_k<<<(NPTS + 255) / 256, 256, 0, stream>>>(gc, vidx, cnt);
    prefix_k<<<1, 256, 0, stream>>>(cnt, offs, cur);
    fill_k<<<(NPTS + 255) / 256, 256, 0, stream>>>(vidx, dprb, cur, pk);

    // segmented-reduction gather
    zero_k<<<(1310720 / 4 + 255) / 256, 256, 0, stream>>>((float4*)accT, 1310720 / 4);
    {
        const int waves = (NPTS + CHUNK - 1) / CHUNK;
        const int blocks = (waves + 3) / 4;
        gather2_k<<<blocks, 256, 0, stream>>>(pk, offs, ctxT, accT);
    }
    transpose_out_k<<<(CCTX * NVOX + 255) / 256, 256, 0, stream>>>(accT, out);

    (void)in_sizes; (void)n_in; (void)out_size; (void)ws_size;
}

// Round 4
// 439.988 us; speedup vs baseline: 1.3735x; 1.1421x over previous
//
#include <hip/hip_runtime.h>

// LSS-FPN round 14: conv with global_load_lds staging + K-split x4.
// Tile 128sp x 128co, 4 waves (2Mx2N, wave 64x64 M2N2, 1 ds_read per MFMA).
// LDS rows 32 B (16 shorts): conflict-free (lh*16 split covers all 8 bank
// quads) AND linear -> global_load_lds width-16 staging, perfectly coalesced
// via ci-chunked layouts xt2[n][32][960][16] / W2[kc][t][co][16].
// K-split x4 -> grid 576 = all blocks co-resident at 3 blk/CU (44 KB LDS),
// fp16 partials (24 chunks in conv-dead WS regions) + combine6.
// Tail (gemm1x1d / softmax2 / binning / gather) unchanged.

#define FH_ 16
#define FW_ 44
#define SP_ 704
#define XSTR 960         // xt rows per image (incl. halo slack)
#define NIMG 6
#define CIN 512
#define DCH 112
#define CCTX 80
#define NXY 128
#define NVOX (NXY * NXY)
#define NPTS (NIMG * DCH * SP_)
#define CHUNK 64

#define NKC6 8           // kc steps per conv block (16 ci each = 128 ci)
#define HCHK 360448      // fp16 partial chunk: 704*512 halves
#define CIP 40           // padded LDS k-stride for gemm1x1 (shorts)

typedef unsigned short u16;
typedef unsigned int u32;
typedef __attribute__((ext_vector_type(8))) short bf16x8;
typedef __attribute__((ext_vector_type(4))) short s16x4;
typedef __attribute__((ext_vector_type(4))) float f32x4;
typedef __attribute__((ext_vector_type(16))) float f32x16;

__device__ __forceinline__ float bf2f(u16 b) {
    union { unsigned u; float f; } v; v.u = ((unsigned)b) << 16; return v.f;
}
__device__ __forceinline__ u16 f2bf(float f) {
    union { float f; unsigned u; } v; v.f = f;
    unsigned r = v.u + 0x7fffu + ((v.u >> 16) & 1u);   // RTNE
    return (u16)(r >> 16);
}
__device__ __forceinline__ int spad_of(int s) {
    return (s / 44) * 46 + (s % 44) + 47;
}
__device__ __forceinline__ void gld_lds16(const void* gsrc, void* ldst) {
    __builtin_amdgcn_global_load_lds(
        (const __attribute__((address_space(1))) u32*)gsrc,
        (__attribute__((address_space(3))) u32*)ldst, 16, 0, 0);
}
// fp16 partial chunk c = q*6+n: chunks 0-5 in dead whiB region (pA),
// chunks 6-23 in post-conv tail region (pB).
__device__ __forceinline__ _Float16* chunk6(_Float16* pA, _Float16* pB, int q, int n) {
    int c = q * 6 + n;
    return (c < 6) ? (pA + (size_t)c * HCHK) : (pB + (size_t)(c - 6) * HCHK);
}

// ---------------- zero fill ---------------------------------------------------
__global__ void zero_k(float4* __restrict__ p, long n4) {
    long i = (long)blockIdx.x * blockDim.x + threadIdx.x;
    if (i < n4) p[i] = make_float4(0.f, 0.f, 0.f, 0.f);
}

// ------- src fp32 [n][ci][704] -> xt2 bf16 chunked [n][32][960][16] ----------
__global__ void src_to_xt_k(const float* __restrict__ src, short* __restrict__ xt) {
    int e = blockIdx.x * 256 + threadIdx.x;
    if (e >= NIMG * SP_ * CIN) return;
    int ci = e & 511;
    int r = e >> 9;
    int s = r % SP_, n = r / SP_;
    float v = src[((size_t)n * CIN + ci) * SP_ + s];
    xt[(((size_t)n * 32 + (ci >> 4)) * XSTR + spad_of(s)) * 16 + (ci & 15)] = (short)f2bf(v);
}

// ------- weight convert: fp32 [co][ci][9] -> W2 bf16 [kc][t][co][16] ---------
__global__ void wsplit_k(const float* __restrict__ w, short* __restrict__ w2) {
    int e = blockIdx.x * 256 + threadIdx.x;
    if (e >= CIN * CIN) return;
    const int co = e >> 9, ci = e & 511;
    const float* wp = w + (size_t)e * 9;
#pragma unroll
    for (int t = 0; t < 9; ++t)
        w2[((((size_t)(ci >> 4) * 9) + t) * CIN + co) * 16 + (ci & 15)] = (short)f2bf(wp[t]);
}

// dual 1x1 weights fp32 [co][ci] -> bf16 (flat [co][ci], unchanged)
__global__ void wsplit1_dual_k(const float* __restrict__ wd, short* __restrict__ od,
                               const float* __restrict__ wc, short* __restrict__ oc) {
    int i = blockIdx.x * 256 + threadIdx.x;
    if (i < DCH * CIN) od[i] = (short)f2bf(wd[i]);
    else if (i < DCH * CIN + CCTX * CIN) {
        int j = i - DCH * CIN;
        oc[j] = (short)f2bf(wc[j]);
    }
}

// ---------------- conv3x3, K-split x4, global_load_lds staging ---------------
// grid 576: bid = (n*6+sb)*16 + (cb*4+q). Block: 128sp x 128co x 128ci.
// 4 waves (mw,nw) each 64sp x 64co (M2N2). fp16 partial out [s][512co].
__global__ __launch_bounds__(256, 3) void conv6_k(
    const short* __restrict__ xt2, const short* __restrict__ w2,
    _Float16* __restrict__ pA, _Float16* __restrict__ pB)
{
    __shared__ short Xs[256 * 16];        // 8,192 B (232 rows used + slack)
    __shared__ short Wsh[1152 * 16];      // 36,864 B
    const int tid = threadIdx.x;
    const int lane = tid & 63, wave = tid >> 6;
    const int l31 = lane & 31, lh = lane >> 5;
    const int mw = wave >> 1, nw = wave & 1;

    const int bid = blockIdx.x;
    const int c16 = bid & 15;
    const int cb = c16 >> 2, q = c16 & 3;
    const int rest = bid >> 4;
    const int n = rest / 6, sb = rest - (rest / 6) * 6;

    const int s0 = sb * 128;
    const int co0 = cb * 128;
    const int base = spad_of(s0) - 47;

    // global bases (shorts): xt2 chunk (n, q*8+kc); W2 chunk (q*8+kc, co0)
    const short* __restrict__ xq = xt2 + (((size_t)n * 32 + q * 8) * XSTR + base) * 16;
    const short* __restrict__ wq = w2 + (((size_t)(q * 8) * 9) * CIN + co0) * 16;

    int sloc[2];
#pragma unroll
    for (int mf = 0; mf < 2; ++mf)
        sloc[mf] = spad_of(s0 + mw * 64 + mf * 32 + l31) - base;

    const f32x16 z16 = {0.f,0.f,0.f,0.f,0.f,0.f,0.f,0.f,
                        0.f,0.f,0.f,0.f,0.f,0.f,0.f,0.f};
    f32x16 acc[2][2];
    acc[0][0] = z16; acc[0][1] = z16; acc[1][0] = z16; acc[1][1] = z16;

    // stage kc chunk: 8 X segments (256 rows) + 36 W segments (9t x 4),
    // each segment = 32 rows x 32 B = 1 KB, contiguous both sides.
    // wave handles segments wave+4i, i=0..10.
#define STAGE6(KC) do {                                                         \
    const short* xc = xq + (size_t)(KC) * (XSTR * 16) + lane * 8;               \
    const short* wc = wq + (size_t)(KC) * (9 * CIN * 16) + lane * 8;            \
    _Pragma("unroll")                                                           \
    for (int i = 0; i < 11; ++i) {                                              \
        const int sg = wave + 4 * i;                                            \
        if (sg < 8) {                                                           \
            gld_lds16(xc + sg * 512, &Xs[sg * 512]);                            \
        } else {                                                                \
            const int j = sg - 8, t = j >> 2, s4 = j & 3;                       \
            gld_lds16(wc + t * (CIN * 16) + s4 * 512, &Wsh[sg * 512 - 4096]);   \
        }                                                                       \
    }                                                                           \
} while (0)

    STAGE6(0);
    __syncthreads();

    constexpr int OFF[9] = {-47, -46, -45, -1, 0, 1, 45, 46, 47};
    for (int kc = 0; kc < NKC6; ++kc) {
#pragma unroll
        for (int t9 = 0; t9 < 9; ++t9) {
            const int off = OFF[t9];
            bf16x8 a0 = *(const bf16x8*)&Xs[(sloc[0] + off) * 16 + lh * 8];
            bf16x8 a1 = *(const bf16x8*)&Xs[(sloc[1] + off) * 16 + lh * 8];
            bf16x8 b0 = *(const bf16x8*)&Wsh[(t9 * 128 + nw * 64 + l31) * 16 + lh * 8];
            bf16x8 b1 = *(const bf16x8*)&Wsh[(t9 * 128 + nw * 64 + 32 + l31) * 16 + lh * 8];
            acc[0][0] = __builtin_amdgcn_mfma_f32_32x32x16_bf16(a0, b0, acc[0][0], 0, 0, 0);
            acc[0][1] = __builtin_amdgcn_mfma_f32_32x32x16_bf16(a0, b1, acc[0][1], 0, 0, 0);
            acc[1][0] = __builtin_amdgcn_mfma_f32_32x32x16_bf16(a1, b0, acc[1][0], 0, 0, 0);
            acc[1][1] = __builtin_amdgcn_mfma_f32_32x32x16_bf16(a1, b1, acc[1][1], 0, 0, 0);
        }
        __syncthreads();                  // all waves done reading LDS
        if (kc + 1 < NKC6) {
            STAGE6(kc + 1);               // async global->LDS, vmcnt-tracked
            __syncthreads();              // drains vmcnt(0) -> staged visible
        }
    }
#undef STAGE6

    // epilogue: fp16 partial; C row = (r&3)+8*(r>>2)+4*lh, col = l31
    _Float16* __restrict__ Pc = chunk6(pA, pB, q, n);
#pragma unroll
    for (int mf = 0; mf < 2; ++mf) {
        const int spb = mw * 64 + mf * 32 + 4 * lh;
#pragma unroll
        for (int r = 0; r < 16; ++r) {
            const int sg = s0 + spb + (r & 3) + 8 * (r >> 2);
            if (sg < SP_) {
                const size_t ro = (size_t)sg * 512 + co0 + nw * 64 + l31;
                Pc[ro] = (_Float16)acc[mf][0][r];
                Pc[ro + 32] = (_Float16)acc[mf][1][r];
            }
        }
    }
}

// ---------------- combine: relu(P0+P1+P2+P3) -> bf16 chunked xt ---------------
__global__ __launch_bounds__(256) void combine6_k(
    _Float16* __restrict__ pA, _Float16* __restrict__ pB, short* __restrict__ xout)
{
    const int i = blockIdx.x * 256 + threadIdx.x;
    if (i >= NIMG * SP_ * CIN / 4) return;
    const int e = i * 4;
    const int n = e / (SP_ * CIN);
    const int r = e - n * (SP_ * CIN);
    const int s = r >> 9, co = r & 511;
    union h4 { s16x4 s; _Float16 h[4]; };
    float v[4] = {0.f, 0.f, 0.f, 0.f};
#pragma unroll
    for (int q = 0; q < 4; ++q) {
        const _Float16* c = chunk6(pA, pB, q, n);
        h4 u; u.s = *(const s16x4*)(c + r);
#pragma unroll
        for (int j = 0; j < 4; ++j) v[j] += (float)u.h[j];
    }
    s16x4 o;
#pragma unroll
    for (int j = 0; j < 4; ++j) o[j] = (short)f2bf(fmaxf(v[j], 0.f));
    *(s16x4*)&xout[(((size_t)n * 32 + (co >> 4)) * XSTR + spad_of(s)) * 16 + (co & 15)] = o;
}

// ---------------- merged 1x1 convs (d2 + c2) as GEMM -------------------------
// grid (6, 2, 6): y=0 -> depth head (NCO=112), y=1 -> context head (NCO=80).
// A read from chunked xt2 layout.
__global__ __launch_bounds__(256, 2) void gemm1x1d_k(
    const short* __restrict__ xA, const short* __restrict__ wA,
    const float* __restrict__ bA, float* __restrict__ oA,
    const short* __restrict__ xB, const short* __restrict__ wB,
    const float* __restrict__ bB, float* __restrict__ oB)
{
    const int sel = blockIdx.y;
    const short* __restrict__ xtin = sel ? xB : xA;
    const short* __restrict__ wb   = sel ? wB : wA;
    const float* __restrict__ bias = sel ? bB : bA;
    float* __restrict__ outT       = sel ? oB : oA;
    const int nst = sel ? (CCTX / 16) : (DCH / 16);   // 5 or 7
    const int nco = nst * 16;

    __shared__ short Wb[DCH * CIP];
    const int tid = threadIdx.x;
    const int s0 = blockIdx.x * 128, n = blockIdx.z;
    const int lane = tid & 63, wave = tid >> 6;
    const int kg = lane >> 4, lrow = lane & 15;
    const int swave = s0 + wave * 32;

    int arow[2];
#pragma unroll
    for (int ms = 0; ms < 2; ++ms)
        arow[ms] = spad_of(swave + ms * 16 + lrow);

    const f32x4 zero4 = {0.f, 0.f, 0.f, 0.f};
    f32x4 acc[2][7];
#pragma unroll
    for (int ms = 0; ms < 2; ++ms)
#pragma unroll
        for (int ns = 0; ns < 7; ++ns) acc[ms][ns] = zero4;

    const short* xb = xtin + (size_t)n * 32 * XSTR * 16;

    for (int kc = 0; kc < 16; ++kc) {
        __syncthreads();
#pragma unroll
        for (int it = 0; it < 2; ++it) {
            int q = it * 256 + tid;
            if (q < nco * 4) {
                int co = q >> 2, p = q & 3;
                *(bf16x8*)&Wb[co * CIP + p * 8] =
                    *(const bf16x8*)(wb + (size_t)co * CIN + kc * 32 + p * 8);
            }
        }
        __syncthreads();
        bf16x8 a[2];
#pragma unroll
        for (int ms = 0; ms < 2; ++ms) {
            const int kcc = 2 * kc + (kg >> 1);
            a[ms] = *(const bf16x8*)(xb + ((size_t)kcc * XSTR + arow[ms]) * 16 + (kg & 1) * 8);
        }
#pragma unroll
        for (int ns = 0; ns < 7; ++ns) {
            if (ns < nst) {
                int co = ns * 16 + lrow;
                bf16x8 b = *(const bf16x8*)&Wb[co * CIP + kg * 8];
#pragma unroll
                for (int ms = 0; ms < 2; ++ms)
                    acc[ms][ns] = __builtin_amdgcn_mfma_f32_16x16x32_bf16(
                        a[ms], b, acc[ms][ns], 0, 0, 0);
            }
        }
    }
#pragma unroll
    for (int ms = 0; ms < 2; ++ms)
#pragma unroll
        for (int ns = 0; ns < 7; ++ns) {
            if (ns < nst) {
#pragma unroll
                for (int r = 0; r < 4; ++r) {
                    int sg = swave + ms * 16 + kg * 4 + r;
                    if (sg < SP_) {
                        int co = ns * 16 + lrow;
                        outT[((size_t)n * SP_ + sg) * nco + co] = acc[ms][ns][r] + bias[co];
                    }
                }
            }
        }
}

// ---------------- softmax over d, layout [n][s][112] (d contiguous) ----------
__global__ __launch_bounds__(256) void softmax2_k(
    const float* __restrict__ lg, float* __restrict__ pr)
{
    const int p = blockIdx.x * 4 + (threadIdx.x >> 6);
    if (p >= NIMG * SP_) return;
    const int lane = threadIdx.x & 63;
    const float* lp = lg + (size_t)p * DCH;
    float v0 = lp[lane];
    float v1 = (lane < DCH - 64) ? lp[64 + lane] : -1e30f;
    float m = fmaxf(v0, v1);
#pragma unroll
    for (int o = 32; o; o >>= 1) m = fmaxf(m, __shfl_xor(m, o));
    float e0 = __expf(v0 - m);
    float e1 = (lane < DCH - 64) ? __expf(v1 - m) : 0.f;
    float s = e0 + e1;
#pragma unroll
    for (int o = 32; o; o >>= 1) s += __shfl_xor(s, o);
    const float inv = 1.f / s;
    float* pp = pr + (size_t)p * DCH;
    pp[lane] = e0 * inv;
    if (lane < DCH - 64) pp[64 + lane] = e1 * inv;
}

// ---------------- per-camera geometry constants (fp64, closed-form) ----------
__device__ __forceinline__ void inv4(const double* M, double* inv) {
    inv[0]  =  M[5]*M[10]*M[15] - M[5]*M[11]*M[14] - M[9]*M[6]*M[15] + M[9]*M[7]*M[14] + M[13]*M[6]*M[11] - M[13]*M[7]*M[10];
    inv[4]  = -M[4]*M[10]*M[15] + M[4]*M[11]*M[14] + M[8]*M[6]*M[15] - M[8]*M[7]*M[14] - M[12]*M[6]*M[11] + M[12]*M[7]*M[10];
    inv[8]  =  M[4]*M[9]*M[15]  - M[4]*M[11]*M[13] - M[8]*M[5]*M[15] + M[8]*M[7]*M[13] + M[12]*M[5]*M[11] - M[12]*M[7]*M[9];
    inv[12] = -M[4]*M[9]*M[14]  + M[4]*M[10]*M[13] + M[8]*M[5]*M[14] - M[8]*M[6]*M[13] - M[12]*M[5]*M[10] + M[12]*M[6]*M[9];
    inv[1]  = -M[1]*M[10]*M[15] + M[1]*M[11]*M[14] + M[9]*M[2]*M[15] - M[9]*M[3]*M[14] - M[13]*M[2]*M[11] + M[13]*M[3]*M[10];
    inv[5]  =  M[0]*M[10]*M[15] - M[0]*M[11]*M[14] - M[8]*M[2]*M[15] + M[8]*M[3]*M[14] + M[12]*M[2]*M[11] - M[12]*M[3]*M[10];
    inv[9]  = -M[0]*M[9]*M[15]  + M[0]*M[11]*M[13] + M[8]*M[1]*M[15] - M[8]*M[3]*M[13] - M[12]*M[1]*M[11] + M[12]*M[3]*M[9];
    inv[13] =  M[0]*M[9]*M[14]  - M[0]*M[10]*M[13] - M[8]*M[1]*M[14] + M[8]*M[2]*M[13] + M[12]*M[1]*M[10] - M[12]*M[2]*M[9];
    inv[2]  =  M[1]*M[6]*M[15]  - M[1]*M[7]*M[14]  - M[5]*M[2]*M[15] + M[5]*M[3]*M[14] + M[13]*M[2]*M[7]  - M[13]*M[3]*M[6];
    inv[6]  = -M[0]*M[6]*M[15]  + M[0]*M[7]*M[14]  + M[4]*M[2]*M[15] - M[4]*M[3]*M[14] - M[12]*M[2]*M[7]  + M[12]*M[3]*M[6];
    inv[10] =  M[0]*M[5]*M[15]  - M[0]*M[7]*M[13]  - M[4]*M[1]*M[15] + M[4]*M[3]*M[13] + M[12]*M[1]*M[7]  - M[12]*M[3]*M[5];
    inv[14] = -M[0]*M[5]*M[14]  + M[0]*M[6]*M[13]  + M[4]*M[1]*M[14] - M[4]*M[2]*M[13] - M[12]*M[1]*M[6]  + M[12]*M[2]*M[5];
    inv[3]  = -M[1]*M[6]*M[11]  + M[1]*M[7]*M[10]  + M[5]*M[2]*M[11] - M[5]*M[3]*M[10] - M[9]*M[2]*M[7]   + M[9]*M[3]*M[6];
    inv[7]  =  M[0]*M[6]*M[11]  - M[0]*M[7]*M[10]  - M[4]*M[2]*M[11] + M[4]*M[3]*M[10] + M[8]*M[2]*M[7]   - M[8]*M[3]*M[6];
    inv[11] = -M[0]*M[5]*M[11]  + M[0]*M[7]*M[9]   + M[4]*M[1]*M[11] - M[4]*M[3]*M[9]  - M[8]*M[1]*M[7]   + M[8]*M[3]*M[5];
    inv[15] =  M[0]*M[5]*M[10]  - M[0]*M[6]*M[9]   - M[4]*M[1]*M[10] + M[4]*M[2]*M[9]  + M[8]*M[1]*M[6]   - M[8]*M[2]*M[5];
    double det = M[0]*inv[0] + M[1]*inv[4] + M[2]*inv[8] + M[3]*inv[12];
    double id = 1.0 / det;
#pragma unroll
    for (int i = 0; i < 16; ++i) inv[i] *= id;
}

__global__ void geom_setup_k(const float* __restrict__ s2e, const float* __restrict__ intrin,
                             const float* __restrict__ ida, const float* __restrict__ bda,
                             double* __restrict__ gc)
{
    const int n = threadIdx.x;
    if (n >= NIMG) return;
    double M[16], Iv[16];
#pragma unroll
    for (int i = 0; i < 16; ++i) M[i] = (double)ida[n * 16 + i];
    inv4(M, Iv);
    double R[3][3], tv[3];
#pragma unroll
    for (int r = 0; r < 3; ++r) {
#pragma unroll
        for (int c = 0; c < 3; ++c) R[r][c] = Iv[r * 4 + c];
        tv[r] = Iv[r * 4 + 3];
    }
    double K[3][3];
#pragma unroll
    for (int r = 0; r < 3; ++r)
#pragma unroll
        for (int c = 0; c < 3; ++c) K[r][c] = (double)intrin[n * 16 + r * 4 + c];
    double det = K[0][0] * (K[1][1] * K[2][2] - K[1][2] * K[2][1])
               - K[0][1] * (K[1][0] * K[2][2] - K[1][2] * K[2][0])
               + K[0][2] * (K[1][0] * K[2][1] - K[1][1] * K[2][0]);
    double id = 1.0 / det;
    double Ki[3][3];
    Ki[0][0] = (K[1][1] * K[2][2] - K[1][2] * K[2][1]) * id;
    Ki[0][1] = (K[0][2] * K[2][1] - K[0][1] * K[2][2]) * id;
    Ki[0][2] = (K[0][1] * K[1][2] - K[0][2] * K[1][1]) * id;
    Ki[1][0] = (K[1][2] * K[2][0] - K[1][0] * K[2][2]) * id;
    Ki[1][1] = (K[0][0] * K[2][2] - K[0][2] * K[2][0]) * id;
    Ki[1][2] = (K[0][2] * K[1][0] - K[0][0] * K[1][2]) * id;
    Ki[2][0] = (K[1][0] * K[2][1] - K[1][1] * K[2][0]) * id;
    Ki[2][1] = (K[0][1] * K[2][0] - K[0][0] * K[2][1]) * id;
    Ki[2][2] = (K[0][0] * K[1][1] - K[0][1] * K[1][0]) * id;
    double A[3][3], bv[3];
#pragma unroll
    for (int r = 0; r < 3; ++r) {
#pragma unroll
        for (int c = 0; c < 3; ++c)
            A[r][c] = Ki[r][0] * R[0][c] + Ki[r][1] * R[1][c] + Ki[r][2] * R[2][c];
        bv[r] = Ki[r][0] * tv[0] + Ki[r][1] * tv[1] + Ki[r][2] * tv[2];
    }
    double* g = gc + n * 24;
#pragma unroll
    for (int r = 0; r < 3; ++r)
#pragma unroll
        for (int c = 0; c < 3; ++c) g[r * 3 + c] = A[r][c];
#pragma unroll
    for (int r = 0; r < 3; ++r) g[9 + r] = bv[r];
#pragma unroll
    for (int r = 0; r < 3; ++r)
#pragma unroll
        for (int c = 0; c < 4; ++c) {
            double acc = 0.0;
#pragma unroll
            for (int k = 0; k < 4; ++k)
                acc += (double)bda[r * 4 + k] * (double)s2e[n * 16 + k * 4 + c];
            g[12 + r * 4 + c] = acc;
        }
}

// ---------------- per-point voxel index + histogram (fused) ------------------
__global__ __launch_bounds__(256) void point_voxel_k(
    const double* __restrict__ gc, int* __restrict__ vidx, int* __restrict__ cnt)
{
    const int i = blockIdx.x * 256 + threadIdx.x;
    if (i >= NPTS) return;
    const int n = i / (DCH * SP_);
    int r = i - n * (DCH * SP_);
    const int di = r / SP_;
    const int s = r - di * SP_;
    const int h = s / FW_, w = s - h * FW_;
    const double* g = gc + n * 24;
    const double u  = (double)(float)((double)w * (703.0 / 43.0));
    const double v  = (double)(float)((double)h * 17.0);
    const double dd = (double)(float)(2.0 + (double)di * (56.0 / 111.0));
    const double rx = g[0] * u + g[1] * v + g[2] + g[9];
    const double ry = g[3] * u + g[4] * v + g[5] + g[10];
    const double rz = g[6] * u + g[7] * v + g[8] + g[11];
    const double px = rx * dd, py = ry * dd, pz = rz * dd;
    const double ex = g[12] * px + g[13] * py + g[14] * pz + g[15];
    const double ey = g[16] * px + g[17] * py + g[18] * pz + g[19];
    const double ez = g[20] * px + g[21] * py + g[22] * pz + g[23];
    const double vs_xy = 0.8, vs_z = 8.0;
    const double offx = (double)(float)(-51.2 + 0.4) - vs_xy * 0.5;
    const double offz = (double)(float)(-5.0 + 4.0) - vs_z * 0.5;
    const int gx = (int)((ex - offx) / vs_xy);
    const int gy = (int)((ey - offx) / vs_xy);
    const int gz = (int)((ez - offz) / vs_z);
    const bool ok = (gx >= 0 && gx < NXY && gy >= 0 && gy < NXY && gz == 0);
    const int vv = ok ? (gy * NXY + gx) : -1;
    vidx[i] = vv;
    if (vv >= 0) atomicAdd(&cnt[vv], 1);
}

// off has NVOX+1 entries; off[NVOX] = total valid points
__global__ void prefix_k(const int* __restrict__ cnt, int* __restrict__ off,
                         int* __restrict__ cur) {
    __shared__ int part[256];
    const int t = threadIdx.x;
    int s = 0;
    for (int j = 0; j < 64; ++j) s += cnt[t * 64 + j];
    part[t] = s;
    __syncthreads();
    if (t == 0) {
        int run = 0;
        for (int k = 0; k < 256; ++k) { int v = part[k]; part[k] = run; run += v; }
    }
    __syncthreads();
    int base = part[t];
    for (int j = 0; j < 64; ++j) {
        off[t * 64 + j] = base;
        cur[t * 64 + j] = base;
        base += cnt[t * 64 + j];
    }
    if (t == 255) off[NVOX] = base;
}

// fill packed entries: key = (v<<13) | (n*SP_+s), prob bits; prob [n][s][112]
__global__ void fill_k(const int* __restrict__ vidx, const float* __restrict__ prob,
                       int* __restrict__ cur, int2* __restrict__ pk) {
    int i = blockIdx.x * 256 + threadIdx.x;
    if (i >= NPTS) return;
    int v = vidx[i];
    if (v < 0) return;
    const int n = i / (DCH * SP_);
    int r = i - n * (DCH * SP_);
    const int di = r / SP_;
    const int s = r - di * SP_;
    int pos = atomicAdd(&cur[v], 1);
    pk[pos] = make_int2((v << 13) | (n * SP_ + s),
                        __float_as_int(prob[((size_t)n * SP_ + s) * DCH + di]));
}

// ---------------- gather: chunk-per-wave segmented reduction ------------------
__global__ __launch_bounds__(256) void gather2_k(
    const int2* __restrict__ pk, const int* __restrict__ off,
    const float* __restrict__ ctxT, float* __restrict__ accT)
{
    const int gtid = blockIdx.x * 256 + threadIdx.x;
    const int wid = gtid >> 6;
    const int lane = threadIdx.x & 63;
    const int total = off[NVOX];
    const int lo = wid * CHUNK;
    if (lo >= total) return;
    const int hi = min(lo + CHUNK, total);
    float a0 = 0.f, a1 = 0.f;
    int2 e = pk[lo];
    for (int k = lo; k < hi; ++k) {
        const int2 en = (k + 1 < hi) ? pk[k + 1] : make_int2(-1, 0);
        const float p = __int_as_float(e.y);
        const int ns = e.x & 8191;
        const float* cb = ctxT + (size_t)ns * CCTX;
        a0 = fmaf(p, cb[lane], a0);
        if (lane < CCTX - 64) a1 = fmaf(p, cb[64 + lane], a1);
        if ((en.x >> 13) != (e.x >> 13)) {         // wave-uniform flush
            float* ab = accT + (size_t)(e.x >> 13) * CCTX;
            atomicAdd(ab + lane, a0);
            if (lane < CCTX - 64) atomicAdd(ab + 64 + lane, a1);
            a0 = a1 = 0.f;
        }
        e = en;
    }
}

// ---------------- transpose accT [v][c] -> out [c][v] ------------------------
__global__ void transpose_out_k(const float* __restrict__ accT, float* __restrict__ out) {
    const int idx = blockIdx.x * 256 + threadIdx.x;
    if (idx >= CCTX * NVOX) return;
    const int c = idx >> 14;
    const int v = idx & 16383;
    out[idx] = accT[(size_t)v * CCTX + c];
}

// ---------------- workspace layout (float offsets) ---------------------------
#define O_WHIA  512           // bf16 conv weights W2 [32][9][512][16]: 1,179,648
#define O_WHIB  1180160       // fp16 partial chunks 0-5 (6 x 180,224 floats)
#define O_XT0   2359808       // 1,474,560  (chunked [n][32][960][16])
#define O_XT1   3834368       // 1,474,560
#define O_XT2   5308928       // 1,474,560
#define O_WD2B  6783488       // fp16 partial chunks 6-23 during conv; then 1x1 wts
#define O_WC2B  6812160       // 20,480 (bf16 80x512)
#define O_DLG   6832640       // 473,088  [n][s][112]
#define O_DPR   7305728       // 473,088
#define O_CTX   7778816       // 337,920  [n][s][80]
#define O_PK    8116736       // 946,176 (int2 x 473,088)
#define O_VIX   9062912       // 473,088
#define O_CNT   9536000       // 16,384
#define O_OFF   9552384       // 16,400
#define O_CUR   9568784       // 16,384
#define O_ACC   9585168       // 1,310,720
// end: 10,895,888 floats = 43.6 MB (unchanged)

extern "C" void kernel_launch(void* const* d_in, const int* in_sizes, int n_in,
                              void* d_out, int out_size, void* d_ws, size_t ws_size,
                              hipStream_t stream)
{
    const float* src  = (const float*)d_in[0];
    const float* w_s1 = (const float*)d_in[1];
    const float* w_s2 = (const float*)d_in[2];
    const float* w_d1 = (const float*)d_in[3];
    const float* w_d2 = (const float*)d_in[4];
    const float* b_d  = (const float*)d_in[5];
    const float* w_c1 = (const float*)d_in[6];
    const float* w_c2 = (const float*)d_in[7];
    const float* b_c  = (const float*)d_in[8];
    const float* s2e  = (const float*)d_in[9];
    const float* intr = (const float*)d_in[10];
    const float* ida  = (const float*)d_in[11];
    const float* bda  = (const float*)d_in[12];

    double* gc = (double*)d_ws;
    float* ws   = (float*)d_ws;
    short* whiA = (short*)(ws + O_WHIA);
    _Float16* pA = (_Float16*)(ws + O_WHIB);     // chunks 0-5
    _Float16* pB = (_Float16*)(ws + O_WD2B);     // chunks 6-23
    short* xt0  = (short*)(ws + O_XT0);
    short* xt1  = (short*)(ws + O_XT1);
    short* xt2  = (short*)(ws + O_XT2);
    short* wd2b = (short*)(ws + O_WD2B);
    short* wc2b = (short*)(ws + O_WC2B);
    float* dlog = ws + O_DLG;
    float* dprb = ws + O_DPR;
    float* ctxT = ws + O_CTX;
    int2*  pk   = (int2*)(ws + O_PK);
    int* vidx   = (int*)(ws + O_VIX);
    int* cnt    = (int*)(ws + O_CNT);
    int* offs   = (int*)(ws + O_OFF);
    int* cur    = (int*)(ws + O_CUR);
    float* accT = ws + O_ACC;
    float* out  = (float*)d_out;

    const int CMB = (NIMG * SP_ * CIN / 4 + 255) / 256;   // 2112 blocks

    // zero xt0+xt1 (contiguous; provides pad borders). xt2 rows fully written
    // by d1-combine before being read -> no zeroing needed.
    zero_k<<<(2949120 / 4 + 255) / 256, 256, 0, stream>>>((float4*)xt0, 2949120 / 4);

    geom_setup_k<<<1, 64, 0, stream>>>(s2e, intr, ida, bda, gc);
    src_to_xt_k<<<(NIMG * SP_ * CIN + 255) / 256, 256, 0, stream>>>(src, xt0);

    // s1: xt0 -> xt1
    wsplit_k<<<(CIN * CIN) / 256, 256, 0, stream>>>(w_s1, whiA);
    conv6_k<<<576, 256, 0, stream>>>(xt0, whiA, pA, pB);
    combine6_k<<<CMB, 256, 0, stream>>>(pA, pB, xt1);
    // s2: xt1 -> xt0
    wsplit_k<<<(CIN * CIN) / 256, 256, 0, stream>>>(w_s2, whiA);
    conv6_k<<<576, 256, 0, stream>>>(xt1, whiA, pA, pB);
    combine6_k<<<CMB, 256, 0, stream>>>(pA, pB, xt0);
    // c1: xt0 -> xt1 (context branch)
    wsplit_k<<<(CIN * CIN) / 256, 256, 0, stream>>>(w_c1, whiA);
    conv6_k<<<576, 256, 0, stream>>>(xt0, whiA, pA, pB);
    combine6_k<<<CMB, 256, 0, stream>>>(pA, pB, xt1);
    // d1: xt0 -> xt2 (depth branch)
    wsplit_k<<<(CIN * CIN) / 256, 256, 0, stream>>>(w_d1, whiA);
    conv6_k<<<576, 256, 0, stream>>>(xt0, whiA, pA, pB);
    combine6_k<<<CMB, 256, 0, stream>>>(pA, pB, xt2);

    // 1x1 weights (both) in one dispatch -- AFTER convs (pB overlap)
    wsplit1_dual_k<<<((DCH + CCTX) * CIN + 255) / 256, 256, 0, stream>>>(w_d2, wd2b, w_c2, wc2b);
    // merged d2 + c2 gemms: xt2 -> dlog [n][s][112], xt1 -> ctxT [n][s][80]
    gemm1x1d_k<<<dim3(6, 2, NIMG), 256, 0, stream>>>(xt2, wd2b, b_d, dlog,
                                                     xt1, wc2b, b_c, ctxT);
    softmax2_k<<<(NIMG * SP_ + 3) / 4, 256, 0, stream>>>(dlog, dprb);

    // binning
    zero_k<<<(NVOX / 4 + 255) / 256, 256, 0, stream>>>((float4*)cnt, NVOX / 4);
    point_voxel_k<<<(NPTS + 255) / 256, 256, 0, stream>>>(gc, vidx, cnt);
    prefix_k<<<1, 256, 0, stream>>>(cnt, offs, cur);
    fill_k<<<(NPTS + 255) / 256, 256, 0, stream>>>(vidx, dprb, cur, pk);

    // segmented-reduction gather
    zero_k<<<(1310720 / 4 + 255) / 256, 256, 0, stream>>>((float4*)accT, 1310720 / 4);
    {
        const int waves = (NPTS + CHUNK - 1) / CHUNK;
        const int blocks = (waves + 3) / 4;
        gather2_k<<<blocks, 256, 0, stream>>>(pk, offs, ctxT, accT);
    }
    transpose_out_k<<<(CCTX * NVOX + 255) / 256, 256, 0, stream>>>(accT, out);

    (void)in_sizes; (void)n_in; (void)out_size; (void)ws_size;
}

// Round 5
// 391.589 us; speedup vs baseline: 1.5432x; 1.1236x over previous
//
#include <hip/hip_runtime.h>

// LSS-FPN round 15: wave-aggregated atomics in point_voxel_k / fill_k.
// R14 counters showed fill_k top-5 at 45us with 0.5% VALU / 5% HBM: same-
// address atomic serialization (near-depth pixel rows land in 1-3 voxels).
// Fix: match-any ballot loop -> one atomicAdd per distinct voxel per wave,
// lanes get pos = base + rank. Conv (global_load_lds K-split x4) unchanged.

#define FH_ 16
#define FW_ 44
#define SP_ 704
#define XSTR 960         // xt rows per image (incl. halo slack)
#define NIMG 6
#define CIN 512
#define DCH 112
#define CCTX 80
#define NXY 128
#define NVOX (NXY * NXY)
#define NPTS (NIMG * DCH * SP_)
#define CHUNK 64

#define NKC6 8           // kc steps per conv block (16 ci each = 128 ci)
#define HCHK 360448      // fp16 partial chunk: 704*512 halves
#define CIP 40           // padded LDS k-stride for gemm1x1 (shorts)

typedef unsigned short u16;
typedef unsigned int u32;
typedef __attribute__((ext_vector_type(8))) short bf16x8;
typedef __attribute__((ext_vector_type(4))) short s16x4;
typedef __attribute__((ext_vector_type(4))) float f32x4;
typedef __attribute__((ext_vector_type(16))) float f32x16;

__device__ __forceinline__ float bf2f(u16 b) {
    union { unsigned u; float f; } v; v.u = ((unsigned)b) << 16; return v.f;
}
__device__ __forceinline__ u16 f2bf(float f) {
    union { float f; unsigned u; } v; v.f = f;
    unsigned r = v.u + 0x7fffu + ((v.u >> 16) & 1u);   // RTNE
    return (u16)(r >> 16);
}
__device__ __forceinline__ int spad_of(int s) {
    return (s / 44) * 46 + (s % 44) + 47;
}
__device__ __forceinline__ void gld_lds16(const void* gsrc, void* ldst) {
    __builtin_amdgcn_global_load_lds(
        (const __attribute__((address_space(1))) u32*)gsrc,
        (__attribute__((address_space(3))) u32*)ldst, 16, 0, 0);
}
// fp16 partial chunk c = q*6+n: chunks 0-5 in dead whiB region (pA),
// chunks 6-23 in post-conv tail region (pB).
__device__ __forceinline__ _Float16* chunk6(_Float16* pA, _Float16* pB, int q, int n) {
    int c = q * 6 + n;
    return (c < 6) ? (pA + (size_t)c * HCHK) : (pB + (size_t)(c - 6) * HCHK);
}

// ---------------- zero fill ---------------------------------------------------
__global__ void zero_k(float4* __restrict__ p, long n4) {
    long i = (long)blockIdx.x * blockDim.x + threadIdx.x;
    if (i < n4) p[i] = make_float4(0.f, 0.f, 0.f, 0.f);
}

// ------- src fp32 [n][ci][704] -> xt2 bf16 chunked [n][32][960][16] ----------
__global__ void src_to_xt_k(const float* __restrict__ src, short* __restrict__ xt) {
    int e = blockIdx.x * 256 + threadIdx.x;
    if (e >= NIMG * SP_ * CIN) return;
    int ci = e & 511;
    int r = e >> 9;
    int s = r % SP_, n = r / SP_;
    float v = src[((size_t)n * CIN + ci) * SP_ + s];
    xt[(((size_t)n * 32 + (ci >> 4)) * XSTR + spad_of(s)) * 16 + (ci & 15)] = (short)f2bf(v);
}

// ------- weight convert: fp32 [co][ci][9] -> W2 bf16 [kc][t][co][16] ---------
__global__ void wsplit_k(const float* __restrict__ w, short* __restrict__ w2) {
    int e = blockIdx.x * 256 + threadIdx.x;
    if (e >= CIN * CIN) return;
    const int co = e >> 9, ci = e & 511;
    const float* wp = w + (size_t)e * 9;
#pragma unroll
    for (int t = 0; t < 9; ++t)
        w2[((((size_t)(ci >> 4) * 9) + t) * CIN + co) * 16 + (ci & 15)] = (short)f2bf(wp[t]);
}

// dual 1x1 weights fp32 [co][ci] -> bf16 (flat [co][ci], unchanged)
__global__ void wsplit1_dual_k(const float* __restrict__ wd, short* __restrict__ od,
                               const float* __restrict__ wc, short* __restrict__ oc) {
    int i = blockIdx.x * 256 + threadIdx.x;
    if (i < DCH * CIN) od[i] = (short)f2bf(wd[i]);
    else if (i < DCH * CIN + CCTX * CIN) {
        int j = i - DCH * CIN;
        oc[j] = (short)f2bf(wc[j]);
    }
}

// ---------------- conv3x3, K-split x4, global_load_lds staging ---------------
// grid 576: bid = (n*6+sb)*16 + (cb*4+q). Block: 128sp x 128co x 128ci.
// 4 waves (mw,nw) each 64sp x 64co (M2N2). fp16 partial out [s][512co].
__global__ __launch_bounds__(256, 3) void conv6_k(
    const short* __restrict__ xt2, const short* __restrict__ w2,
    _Float16* __restrict__ pA, _Float16* __restrict__ pB)
{
    __shared__ short Xs[256 * 16];        // 8,192 B (232 rows used + slack)
    __shared__ short Wsh[1152 * 16];      // 36,864 B
    const int tid = threadIdx.x;
    const int lane = tid & 63, wave = tid >> 6;
    const int l31 = lane & 31, lh = lane >> 5;
    const int mw = wave >> 1, nw = wave & 1;

    const int bid = blockIdx.x;
    const int c16 = bid & 15;
    const int cb = c16 >> 2, q = c16 & 3;
    const int rest = bid >> 4;
    const int n = rest / 6, sb = rest - (rest / 6) * 6;

    const int s0 = sb * 128;
    const int co0 = cb * 128;
    const int base = spad_of(s0) - 47;

    // global bases (shorts): xt2 chunk (n, q*8+kc); W2 chunk (q*8+kc, co0)
    const short* __restrict__ xq = xt2 + (((size_t)n * 32 + q * 8) * XSTR + base) * 16;
    const short* __restrict__ wq = w2 + (((size_t)(q * 8) * 9) * CIN + co0) * 16;

    int sloc[2];
#pragma unroll
    for (int mf = 0; mf < 2; ++mf)
        sloc[mf] = spad_of(s0 + mw * 64 + mf * 32 + l31) - base;

    const f32x16 z16 = {0.f,0.f,0.f,0.f,0.f,0.f,0.f,0.f,
                        0.f,0.f,0.f,0.f,0.f,0.f,0.f,0.f};
    f32x16 acc[2][2];
    acc[0][0] = z16; acc[0][1] = z16; acc[1][0] = z16; acc[1][1] = z16;

    // stage kc chunk: 8 X segments (256 rows) + 36 W segments (9t x 4),
    // each segment = 32 rows x 32 B = 1 KB, contiguous both sides.
    // wave handles segments wave+4i, i=0..10.
#define STAGE6(KC) do {                                                         \
    const short* xc = xq + (size_t)(KC) * (XSTR * 16) + lane * 8;               \
    const short* wc = wq + (size_t)(KC) * (9 * CIN * 16) + lane * 8;            \
    _Pragma("unroll")                                                           \
    for (int i = 0; i < 11; ++i) {                                              \
        const int sg = wave + 4 * i;                                            \
        if (sg < 8) {                                                           \
            gld_lds16(xc + sg * 512, &Xs[sg * 512]);                            \
        } else {                                                                \
            const int j = sg - 8, t = j >> 2, s4 = j & 3;                       \
            gld_lds16(wc + t * (CIN * 16) + s4 * 512, &Wsh[sg * 512 - 4096]);   \
        }                                                                       \
    }                                                                           \
} while (0)

    STAGE6(0);
    __syncthreads();

    constexpr int OFF[9] = {-47, -46, -45, -1, 0, 1, 45, 46, 47};
    for (int kc = 0; kc < NKC6; ++kc) {
#pragma unroll
        for (int t9 = 0; t9 < 9; ++t9) {
            const int off = OFF[t9];
            bf16x8 a0 = *(const bf16x8*)&Xs[(sloc[0] + off) * 16 + lh * 8];
            bf16x8 a1 = *(const bf16x8*)&Xs[(sloc[1] + off) * 16 + lh * 8];
            bf16x8 b0 = *(const bf16x8*)&Wsh[(t9 * 128 + nw * 64 + l31) * 16 + lh * 8];
            bf16x8 b1 = *(const bf16x8*)&Wsh[(t9 * 128 + nw * 64 + 32 + l31) * 16 + lh * 8];
            acc[0][0] = __builtin_amdgcn_mfma_f32_32x32x16_bf16(a0, b0, acc[0][0], 0, 0, 0);
            acc[0][1] = __builtin_amdgcn_mfma_f32_32x32x16_bf16(a0, b1, acc[0][1], 0, 0, 0);
            acc[1][0] = __builtin_amdgcn_mfma_f32_32x32x16_bf16(a1, b0, acc[1][0], 0, 0, 0);
            acc[1][1] = __builtin_amdgcn_mfma_f32_32x32x16_bf16(a1, b1, acc[1][1], 0, 0, 0);
        }
        __syncthreads();                  // all waves done reading LDS
        if (kc + 1 < NKC6) {
            STAGE6(kc + 1);               // async global->LDS, vmcnt-tracked
            __syncthreads();              // drains vmcnt(0) -> staged visible
        }
    }
#undef STAGE6

    // epilogue: fp16 partial; C row = (r&3)+8*(r>>2)+4*lh, col = l31
    _Float16* __restrict__ Pc = chunk6(pA, pB, q, n);
#pragma unroll
    for (int mf = 0; mf < 2; ++mf) {
        const int spb = mw * 64 + mf * 32 + 4 * lh;
#pragma unroll
        for (int r = 0; r < 16; ++r) {
            const int sg = s0 + spb + (r & 3) + 8 * (r >> 2);
            if (sg < SP_) {
                const size_t ro = (size_t)sg * 512 + co0 + nw * 64 + l31;
                Pc[ro] = (_Float16)acc[mf][0][r];
                Pc[ro + 32] = (_Float16)acc[mf][1][r];
            }
        }
    }
}

// ---------------- combine: relu(P0+P1+P2+P3) -> bf16 chunked xt ---------------
__global__ __launch_bounds__(256) void combine6_k(
    _Float16* __restrict__ pA, _Float16* __restrict__ pB, short* __restrict__ xout)
{
    const int i = blockIdx.x * 256 + threadIdx.x;
    if (i >= NIMG * SP_ * CIN / 4) return;
    const int e = i * 4;
    const int n = e / (SP_ * CIN);
    const int r = e - n * (SP_ * CIN);
    const int s = r >> 9, co = r & 511;
    union h4 { s16x4 s; _Float16 h[4]; };
    float v[4] = {0.f, 0.f, 0.f, 0.f};
#pragma unroll
    for (int q = 0; q < 4; ++q) {
        const _Float16* c = chunk6(pA, pB, q, n);
        h4 u; u.s = *(const s16x4*)(c + r);
#pragma unroll
        for (int j = 0; j < 4; ++j) v[j] += (float)u.h[j];
    }
    s16x4 o;
#pragma unroll
    for (int j = 0; j < 4; ++j) o[j] = (short)f2bf(fmaxf(v[j], 0.f));
    *(s16x4*)&xout[(((size_t)n * 32 + (co >> 4)) * XSTR + spad_of(s)) * 16 + (co & 15)] = o;
}

// ---------------- merged 1x1 convs (d2 + c2) as GEMM -------------------------
// grid (6, 2, 6): y=0 -> depth head (NCO=112), y=1 -> context head (NCO=80).
// A read from chunked xt2 layout.
__global__ __launch_bounds__(256, 2) void gemm1x1d_k(
    const short* __restrict__ xA, const short* __restrict__ wA,
    const float* __restrict__ bA, float* __restrict__ oA,
    const short* __restrict__ xB, const short* __restrict__ wB,
    const float* __restrict__ bB, float* __restrict__ oB)
{
    const int sel = blockIdx.y;
    const short* __restrict__ xtin = sel ? xB : xA;
    const short* __restrict__ wb   = sel ? wB : wA;
    const float* __restrict__ bias = sel ? bB : bA;
    float* __restrict__ outT       = sel ? oB : oA;
    const int nst = sel ? (CCTX / 16) : (DCH / 16);   // 5 or 7
    const int nco = nst * 16;

    __shared__ short Wb[DCH * CIP];
    const int tid = threadIdx.x;
    const int s0 = blockIdx.x * 128, n = blockIdx.z;
    const int lane = tid & 63, wave = tid >> 6;
    const int kg = lane >> 4, lrow = lane & 15;
    const int swave = s0 + wave * 32;

    int arow[2];
#pragma unroll
    for (int ms = 0; ms < 2; ++ms)
        arow[ms] = spad_of(swave + ms * 16 + lrow);

    const f32x4 zero4 = {0.f, 0.f, 0.f, 0.f};
    f32x4 acc[2][7];
#pragma unroll
    for (int ms = 0; ms < 2; ++ms)
#pragma unroll
        for (int ns = 0; ns < 7; ++ns) acc[ms][ns] = zero4;

    const short* xb = xtin + (size_t)n * 32 * XSTR * 16;

    for (int kc = 0; kc < 16; ++kc) {
        __syncthreads();
#pragma unroll
        for (int it = 0; it < 2; ++it) {
            int q = it * 256 + tid;
            if (q < nco * 4) {
                int co = q >> 2, p = q & 3;
                *(bf16x8*)&Wb[co * CIP + p * 8] =
                    *(const bf16x8*)(wb + (size_t)co * CIN + kc * 32 + p * 8);
            }
        }
        __syncthreads();
        bf16x8 a[2];
#pragma unroll
        for (int ms = 0; ms < 2; ++ms) {
            const int kcc = 2 * kc + (kg >> 1);
            a[ms] = *(const bf16x8*)(xb + ((size_t)kcc * XSTR + arow[ms]) * 16 + (kg & 1) * 8);
        }
#pragma unroll
        for (int ns = 0; ns < 7; ++ns) {
            if (ns < nst) {
                int co = ns * 16 + lrow;
                bf16x8 b = *(const bf16x8*)&Wb[co * CIP + kg * 8];
#pragma unroll
                for (int ms = 0; ms < 2; ++ms)
                    acc[ms][ns] = __builtin_amdgcn_mfma_f32_16x16x32_bf16(
                        a[ms], b, acc[ms][ns], 0, 0, 0);
            }
        }
    }
#pragma unroll
    for (int ms = 0; ms < 2; ++ms)
#pragma unroll
        for (int ns = 0; ns < 7; ++ns) {
            if (ns < nst) {
#pragma unroll
                for (int r = 0; r < 4; ++r) {
                    int sg = swave + ms * 16 + kg * 4 + r;
                    if (sg < SP_) {
                        int co = ns * 16 + lrow;
                        outT[((size_t)n * SP_ + sg) * nco + co] = acc[ms][ns][r] + bias[co];
                    }
                }
            }
        }
}

// ---------------- softmax over d, layout [n][s][112] (d contiguous) ----------
__global__ __launch_bounds__(256) void softmax2_k(
    const float* __restrict__ lg, float* __restrict__ pr)
{
    const int p = blockIdx.x * 4 + (threadIdx.x >> 6);
    if (p >= NIMG * SP_) return;
    const int lane = threadIdx.x & 63;
    const float* lp = lg + (size_t)p * DCH;
    float v0 = lp[lane];
    float v1 = (lane < DCH - 64) ? lp[64 + lane] : -1e30f;
    float m = fmaxf(v0, v1);
#pragma unroll
    for (int o = 32; o; o >>= 1) m = fmaxf(m, __shfl_xor(m, o));
    float e0 = __expf(v0 - m);
    float e1 = (lane < DCH - 64) ? __expf(v1 - m) : 0.f;
    float s = e0 + e1;
#pragma unroll
    for (int o = 32; o; o >>= 1) s += __shfl_xor(s, o);
    const float inv = 1.f / s;
    float* pp = pr + (size_t)p * DCH;
    pp[lane] = e0 * inv;
    if (lane < DCH - 64) pp[64 + lane] = e1 * inv;
}

// ---------------- per-camera geometry constants (fp64, closed-form) ----------
__device__ __forceinline__ void inv4(const double* M, double* inv) {
    inv[0]  =  M[5]*M[10]*M[15] - M[5]*M[11]*M[14] - M[9]*M[6]*M[15] + M[9]*M[7]*M[14] + M[13]*M[6]*M[11] - M[13]*M[7]*M[10];
    inv[4]  = -M[4]*M[10]*M[15] + M[4]*M[11]*M[14] + M[8]*M[6]*M[15] - M[8]*M[7]*M[14] - M[12]*M[6]*M[11] + M[12]*M[7]*M[10];
    inv[8]  =  M[4]*M[9]*M[15]  - M[4]*M[11]*M[13] - M[8]*M[5]*M[15] + M[8]*M[7]*M[13] + M[12]*M[5]*M[11] - M[12]*M[7]*M[9];
    inv[12] = -M[4]*M[9]*M[14]  + M[4]*M[10]*M[13] + M[8]*M[5]*M[14] - M[8]*M[6]*M[13] - M[12]*M[5]*M[10] + M[12]*M[6]*M[9];
    inv[1]  = -M[1]*M[10]*M[15] + M[1]*M[11]*M[14] + M[9]*M[2]*M[15] - M[9]*M[3]*M[14] - M[13]*M[2]*M[11] + M[13]*M[3]*M[10];
    inv[5]  =  M[0]*M[10]*M[15] - M[0]*M[11]*M[14] - M[8]*M[2]*M[15] + M[8]*M[3]*M[14] + M[12]*M[2]*M[11] - M[12]*M[3]*M[10];
    inv[9]  = -M[0]*M[9]*M[15]  + M[0]*M[11]*M[13] + M[8]*M[1]*M[15] - M[8]*M[3]*M[13] - M[12]*M[1]*M[11] + M[12]*M[3]*M[9];
    inv[13] =  M[0]*M[9]*M[14]  - M[0]*M[10]*M[13] - M[8]*M[1]*M[14] + M[8]*M[2]*M[13] + M[12]*M[1]*M[10] - M[12]*M[2]*M[9];
    inv[2]  =  M[1]*M[6]*M[15]  - M[1]*M[7]*M[14]  - M[5]*M[2]*M[15] + M[5]*M[3]*M[14] + M[13]*M[2]*M[7]  - M[13]*M[3]*M[6];
    inv[6]  = -M[0]*M[6]*M[15]  + M[0]*M[7]*M[14]  + M[4]*M[2]*M[15] - M[4]*M[3]*M[14] - M[12]*M[2]*M[7]  + M[12]*M[3]*M[6];
    inv[10] =  M[0]*M[5]*M[15]  - M[0]*M[7]*M[13]  - M[4]*M[1]*M[15] + M[4]*M[3]*M[13] + M[12]*M[1]*M[7]  - M[12]*M[3]*M[5];
    inv[14] = -M[0]*M[5]*M[14]  + M[0]*M[6]*M[13]  + M[4]*M[1]*M[14] - M[4]*M[2]*M[13] - M[12]*M[1]*M[6]  + M[12]*M[2]*M[5];
    inv[3]  = -M[1]*M[6]*M[11]  + M[1]*M[7]*M[10]  + M[5]*M[2]*M[11] - M[5]*M[3]*M[10] - M[9]*M[2]*M[7]   + M[9]*M[3]*M[6];
    inv[7]  =  M[0]*M[6]*M[11]  - M[0]*M[7]*M[10]  - M[4]*M[2]*M[11] + M[4]*M[3]*M[10] + M[8]*M[2]*M[7]   - M[8]*M[3]*M[6];
    inv[11] = -M[0]*M[5]*M[11]  + M[0]*M[7]*M[9]   + M[4]*M[1]*M[11] - M[4]*M[3]*M[9]  - M[8]*M[1]*M[7]   + M[8]*M[3]*M[5];
    inv[15] =  M[0]*M[5]*M[10]  - M[0]*M[6]*M[9]   - M[4]*M[1]*M[10] + M[4]*M[2]*M[9]  + M[8]*M[1]*M[6]   - M[8]*M[2]*M[5];
    double det = M[0]*inv[0] + M[1]*inv[4] + M[2]*inv[8] + M[3]*inv[12];
    double id = 1.0 / det;
#pragma unroll
    for (int i = 0; i < 16; ++i) inv[i] *= id;
}

__global__ void geom_setup_k(const float* __restrict__ s2e, const float* __restrict__ intrin,
                             const float* __restrict__ ida, const float* __restrict__ bda,
                             double* __restrict__ gc)
{
    const int n = threadIdx.x;
    if (n >= NIMG) return;
    double M[16], Iv[16];
#pragma unroll
    for (int i = 0; i < 16; ++i) M[i] = (double)ida[n * 16 + i];
    inv4(M, Iv);
    double R[3][3], tv[3];
#pragma unroll
    for (int r = 0; r < 3; ++r) {
#pragma unroll
        for (int c = 0; c < 3; ++c) R[r][c] = Iv[r * 4 + c];
        tv[r] = Iv[r * 4 + 3];
    }
    double K[3][3];
#pragma unroll
    for (int r = 0; r < 3; ++r)
#pragma unroll
        for (int c = 0; c < 3; ++c) K[r][c] = (double)intrin[n * 16 + r * 4 + c];
    double det = K[0][0] * (K[1][1] * K[2][2] - K[1][2] * K[2][1])
               - K[0][1] * (K[1][0] * K[2][2] - K[1][2] * K[2][0])
               + K[0][2] * (K[1][0] * K[2][1] - K[1][1] * K[2][0]);
    double id = 1.0 / det;
    double Ki[3][3];
    Ki[0][0] = (K[1][1] * K[2][2] - K[1][2] * K[2][1]) * id;
    Ki[0][1] = (K[0][2] * K[2][1] - K[0][1] * K[2][2]) * id;
    Ki[0][2] = (K[0][1] * K[1][2] - K[0][2] * K[1][1]) * id;
    Ki[1][0] = (K[1][2] * K[2][0] - K[1][0] * K[2][2]) * id;
    Ki[1][1] = (K[0][0] * K[2][2] - K[0][2] * K[2][0]) * id;
    Ki[1][2] = (K[0][2] * K[1][0] - K[0][0] * K[1][2]) * id;
    Ki[2][0] = (K[1][0] * K[2][1] - K[1][1] * K[2][0]) * id;
    Ki[2][1] = (K[0][1] * K[2][0] - K[0][0] * K[2][1]) * id;
    Ki[2][2] = (K[0][0] * K[1][1] - K[0][1] * K[1][0]) * id;
    double A[3][3], bv[3];
#pragma unroll
    for (int r = 0; r < 3; ++r) {
#pragma unroll
        for (int c = 0; c < 3; ++c)
            A[r][c] = Ki[r][0] * R[0][c] + Ki[r][1] * R[1][c] + Ki[r][2] * R[2][c];
        bv[r] = Ki[r][0] * tv[0] + Ki[r][1] * tv[1] + Ki[r][2] * tv[2];
    }
    double* g = gc + n * 24;
#pragma unroll
    for (int r = 0; r < 3; ++r)
#pragma unroll
        for (int c = 0; c < 3; ++c) g[r * 3 + c] = A[r][c];
#pragma unroll
    for (int r = 0; r < 3; ++r) g[9 + r] = bv[r];
#pragma unroll
    for (int r = 0; r < 3; ++r)
#pragma unroll
        for (int c = 0; c < 4; ++c) {
            double acc = 0.0;
#pragma unroll
            for (int k = 0; k < 4; ++k)
                acc += (double)bda[r * 4 + k] * (double)s2e[n * 16 + k * 4 + c];
            g[12 + r * 4 + c] = acc;
        }
}

// ---------------- per-point voxel index + histogram (wave-aggregated) --------
__global__ __launch_bounds__(256) void point_voxel_k(
    const double* __restrict__ gc, int* __restrict__ vidx, int* __restrict__ cnt)
{
    const int i = blockIdx.x * 256 + threadIdx.x;
    if (i >= NPTS) return;
    const int lane = threadIdx.x & 63;
    const int n = i / (DCH * SP_);
    int r = i - n * (DCH * SP_);
    const int di = r / SP_;
    const int s = r - di * SP_;
    const int h = s / FW_, w = s - h * FW_;
    const double* g = gc + n * 24;
    const double u  = (double)(float)((double)w * (703.0 / 43.0));
    const double v  = (double)(float)((double)h * 17.0);
    const double dd = (double)(float)(2.0 + (double)di * (56.0 / 111.0));
    const double rx = g[0] * u + g[1] * v + g[2] + g[9];
    const double ry = g[3] * u + g[4] * v + g[5] + g[10];
    const double rz = g[6] * u + g[7] * v + g[8] + g[11];
    const double px = rx * dd, py = ry * dd, pz = rz * dd;
    const double ex = g[12] * px + g[13] * py + g[14] * pz + g[15];
    const double ey = g[16] * px + g[17] * py + g[18] * pz + g[19];
    const double ez = g[20] * px + g[21] * py + g[22] * pz + g[23];
    const double vs_xy = 0.8, vs_z = 8.0;
    const double offx = (double)(float)(-51.2 + 0.4) - vs_xy * 0.5;
    const double offz = (double)(float)(-5.0 + 4.0) - vs_z * 0.5;
    const int gx = (int)((ex - offx) / vs_xy);
    const int gy = (int)((ey - offx) / vs_xy);
    const int gz = (int)((ez - offz) / vs_z);
    const bool ok = (gx >= 0 && gx < NXY && gy >= 0 && gy < NXY && gz == 0);
    const int vv = ok ? (gy * NXY + gx) : -1;
    vidx[i] = vv;
    // wave-aggregated histogram: one atomic per distinct voxel per wave
    unsigned long long unresolved = __ballot(vv >= 0);
    while (unresolved) {
        const int src = __ffsll(unresolved) - 1;
        const int v0 = __shfl(vv, src);
        const unsigned long long grp = __ballot(vv == v0);
        if (lane == src) atomicAdd(&cnt[v0], __popcll(grp));
        unresolved &= ~grp;
    }
}

// off has NVOX+1 entries; off[NVOX] = total valid points
__global__ void prefix_k(const int* __restrict__ cnt, int* __restrict__ off,
                         int* __restrict__ cur) {
    __shared__ int part[256];
    const int t = threadIdx.x;
    int s = 0;
    for (int j = 0; j < 64; ++j) s += cnt[t * 64 + j];
    part[t] = s;
    __syncthreads();
    if (t == 0) {
        int run = 0;
        for (int k = 0; k < 256; ++k) { int v = part[k]; part[k] = run; run += v; }
    }
    __syncthreads();
    int base = part[t];
    for (int j = 0; j < 64; ++j) {
        off[t * 64 + j] = base;
        cur[t * 64 + j] = base;
        base += cnt[t * 64 + j];
    }
    if (t == 255) off[NVOX] = base;
}

// fill packed entries: key = (v<<13) | (n*SP_+s), prob bits; prob [n][s][112]
// wave-aggregated: one atomicAdd per distinct voxel per wave, pos=base+rank.
__global__ __launch_bounds__(256) void fill_k(
    const int* __restrict__ vidx, const float* __restrict__ prob,
    int* __restrict__ cur, int2* __restrict__ pk) {
    int i = blockIdx.x * 256 + threadIdx.x;
    if (i >= NPTS) return;
    const int lane = threadIdx.x & 63;
    const int v = vidx[i];
    const int n = i / (DCH * SP_);
    int r = i - n * (DCH * SP_);
    const int di = r / SP_;
    const int s = r - di * SP_;
    float p = 0.f;
    if (v >= 0) p = prob[((size_t)n * SP_ + s) * DCH + di];

    int pos = -1;
    unsigned long long unresolved = __ballot(v >= 0);
    while (unresolved) {
        const int src = __ffsll(unresolved) - 1;
        const int v0 = __shfl(v, src);
        const unsigned long long grp = __ballot(v == v0);
        int base = 0;
        if (lane == src) base = atomicAdd(&cur[v0], __popcll(grp));
        base = __shfl(base, src);
        if (v == v0) {
            const int rank = __popcll(grp & ((1ull << lane) - 1ull));
            pos = base + rank;
        }
        unresolved &= ~grp;
    }
    if (v >= 0)
        pk[pos] = make_int2((v << 13) | (n * SP_ + s), __float_as_int(p));
}

// ---------------- gather: chunk-per-wave segmented reduction ------------------
__global__ __launch_bounds__(256) void gather2_k(
    const int2* __restrict__ pk, const int* __restrict__ off,
    const float* __restrict__ ctxT, float* __restrict__ accT)
{
    const int gtid = blockIdx.x * 256 + threadIdx.x;
    const int wid = gtid >> 6;
    const int lane = threadIdx.x & 63;
    const int total = off[NVOX];
    const int lo = wid * CHUNK;
    if (lo >= total) return;
    const int hi = min(lo + CHUNK, total);
    float a0 = 0.f, a1 = 0.f;
    int2 e = pk[lo];
    for (int k = lo; k < hi; ++k) {
        const int2 en = (k + 1 < hi) ? pk[k + 1] : make_int2(-1, 0);
        const float p = __int_as_float(e.y);
        const int ns = e.x & 8191;
        const float* cb = ctxT + (size_t)ns * CCTX;
        a0 = fmaf(p, cb[lane], a0);
        if (lane < CCTX - 64) a1 = fmaf(p, cb[64 + lane], a1);
        if ((en.x >> 13) != (e.x >> 13)) {         // wave-uniform flush
            float* ab = accT + (size_t)(e.x >> 13) * CCTX;
            atomicAdd(ab + lane, a0);
            if (lane < CCTX - 64) atomicAdd(ab + 64 + lane, a1);
            a0 = a1 = 0.f;
        }
        e = en;
    }
}

// ---------------- transpose accT [v][c] -> out [c][v] ------------------------
__global__ void transpose_out_k(const float* __restrict__ accT, float* __restrict__ out) {
    const int idx = blockIdx.x * 256 + threadIdx.x;
    if (idx >= CCTX * NVOX) return;
    const int c = idx >> 14;
    const int v = idx & 16383;
    out[idx] = accT[(size_t)v * CCTX + c];
}

// ---------------- workspace layout (float offsets) ---------------------------
#define O_WHIA  512           // bf16 conv weights W2 [32][9][512][16]: 1,179,648
#define O_WHIB  1180160       // fp16 partial chunks 0-5 (6 x 180,224 floats)
#define O_XT0   2359808       // 1,474,560  (chunked [n][32][960][16])
#define O_XT1   3834368       // 1,474,560
#define O_XT2   5308928       // 1,474,560
#define O_WD2B  6783488       // fp16 partial chunks 6-23 during conv; then 1x1 wts
#define O_WC2B  6812160       // 20,480 (bf16 80x512)
#define O_DLG   6832640       // 473,088  [n][s][112]
#define O_DPR   7305728       // 473,088
#define O_CTX   7778816       // 337,920  [n][s][80]
#define O_PK    8116736       // 946,176 (int2 x 473,088)
#define O_VIX   9062912       // 473,088
#define O_CNT   9536000       // 16,384
#define O_OFF   9552384       // 16,400
#define O_CUR   9568784       // 16,384
#define O_ACC   9585168       // 1,310,720
// end: 10,895,888 floats = 43.6 MB (unchanged)

extern "C" void kernel_launch(void* const* d_in, const int* in_sizes, int n_in,
                              void* d_out, int out_size, void* d_ws, size_t ws_size,
                              hipStream_t stream)
{
    const float* src  = (const float*)d_in[0];
    const float* w_s1 = (const float*)d_in[1];
    const float* w_s2 = (const float*)d_in[2];
    const float* w_d1 = (const float*)d_in[3];
    const float* w_d2 = (const float*)d_in[4];
    const float* b_d  = (const float*)d_in[5];
    const float* w_c1 = (const float*)d_in[6];
    const float* w_c2 = (const float*)d_in[7];
    const float* b_c  = (const float*)d_in[8];
    const float* s2e  = (const float*)d_in[9];
    const float* intr = (const float*)d_in[10];
    const float* ida  = (const float*)d_in[11];
    const float* bda  = (const float*)d_in[12];

    double* gc = (double*)d_ws;
    float* ws   = (float*)d_ws;
    short* whiA = (short*)(ws + O_WHIA);
    _Float16* pA = (_Float16*)(ws + O_WHIB);     // chunks 0-5
    _Float16* pB = (_Float16*)(ws + O_WD2B);     // chunks 6-23
    short* xt0  = (short*)(ws + O_XT0);
    short* xt1  = (short*)(ws + O_XT1);
    short* xt2  = (short*)(ws + O_XT2);
    short* wd2b = (short*)(ws + O_WD2B);
    short* wc2b = (short*)(ws + O_WC2B);
    float* dlog = ws + O_DLG;
    float* dprb = ws + O_DPR;
    float* ctxT = ws + O_CTX;
    int2*  pk   = (int2*)(ws + O_PK);
    int* vidx   = (int*)(ws + O_VIX);
    int* cnt    = (int*)(ws + O_CNT);
    int* offs   = (int*)(ws + O_OFF);
    int* cur    = (int*)(ws + O_CUR);
    float* accT = ws + O_ACC;
    float* out  = (float*)d_out;

    const int CMB = (NIMG * SP_ * CIN / 4 + 255) / 256;   // 2112 blocks

    // zero xt0+xt1 (contiguous; provides pad borders). xt2 rows fully written
    // by d1-combine before being read -> no zeroing needed.
    zero_k<<<(2949120 / 4 + 255) / 256, 256, 0, stream>>>((float4*)xt0, 2949120 / 4);

    geom_setup_k<<<1, 64, 0, stream>>>(s2e, intr, ida, bda, gc);
    src_to_xt_k<<<(NIMG * SP_ * CIN + 255) / 256, 256, 0, stream>>>(src, xt0);

    // s1: xt0 -> xt1
    wsplit_k<<<(CIN * CIN) / 256, 256, 0, stream>>>(w_s1, whiA);
    conv6_k<<<576, 256, 0, stream>>>(xt0, whiA, pA, pB);
    combine6_k<<<CMB, 256, 0, stream>>>(pA, pB, xt1);
    // s2: xt1 -> xt0
    wsplit_k<<<(CIN * CIN) / 256, 256, 0, stream>>>(w_s2, whiA);
    conv6_k<<<576, 256, 0, stream>>>(xt1, whiA, pA, pB);
    combine6_k<<<CMB, 256, 0, stream>>>(pA, pB, xt0);
    // c1: xt0 -> xt1 (context branch)
    wsplit_k<<<(CIN * CIN) / 256, 256, 0, stream>>>(w_c1, whiA);
    conv6_k<<<576, 256, 0, stream>>>(xt0, whiA, pA, pB);
    combine6_k<<<CMB, 256, 0, stream>>>(pA, pB, xt1);
    // d1: xt0 -> xt2 (depth branch)
    wsplit_k<<<(CIN * CIN) / 256, 256, 0, stream>>>(w_d1, whiA);
    conv6_k<<<576, 256, 0, stream>>>(xt0, whiA, pA, pB);
    combine6_k<<<CMB, 256, 0, stream>>>(pA, pB, xt2);

    // 1x1 weights (both) in one dispatch -- AFTER convs (pB overlap)
    wsplit1_dual_k<<<((DCH + CCTX) * CIN + 255) / 256, 256, 0, stream>>>(w_d2, wd2b, w_c2, wc2b);
    // merged d2 + c2 gemms: xt2 -> dlog [n][s][112], xt1 -> ctxT [n][s][80]
    gemm1x1d_k<<<dim3(6, 2, NIMG), 256, 0, stream>>>(xt2, wd2b, b_d, dlog,
                                                     xt1, wc2b, b_c, ctxT);
    softmax2_k<<<(NIMG * SP_ + 3) / 4, 256, 0, stream>>>(dlog, dprb);

    // binning
    zero_k<<<(NVOX / 4 + 255) / 256, 256, 0, stream>>>((float4*)cnt, NVOX / 4);
    point_voxel_k<<<(NPTS + 255) / 256, 256, 0, stream>>>(gc, vidx, cnt);
    prefix_k<<<1, 256, 0, stream>>>(cnt, offs, cur);
    fill_k<<<(NPTS + 255) / 256, 256, 0, stream>>>(vidx, dprb, cur, pk);

    // segmented-reduction gather
    zero_k<<<(1310720 / 4 + 255) / 256, 256, 0, stream>>>((float4*)accT, 1310720 / 4);
    {
        const int waves = (NPTS + CHUNK - 1) / CHUNK;
        const int blocks = (waves + 3) / 4;
        gather2_k<<<blocks, 256, 0, stream>>>(pk, offs, ctxT, accT);
    }
    transpose_out_k<<<(CCTX * NVOX + 255) / 256, 256, 0, stream>>>(accT, out);

    (void)in_sizes; (void)n_in; (void)out_size; (void)ws_size;
}